// Round 1
// baseline (2312.444 us; speedup 1.0000x reference)
//
#include <hip/hip_runtime.h>
#include <math.h>

// ---------------------------------------------------------------------------
// NystromAttention fp32 implementation (round 1: correctness-first).
// b=4 n=4096 dim=512 h=8 d=64 m=256 landmarks, l=16, pinv iters=6, conv k=33.
//
// ws layout (floats):
//   q (also reused as out_heads) | k | v | ql | kl | x2(attn2) | z0 | z1 |
//   xz | t1 | t2 | av | w2 | marr | larr | scal[2]
// total ~159.5 MB.
// ---------------------------------------------------------------------------

#define NSEQ 4096
#define NBH 32          // b*h
#define QKV_STRIDE 262144   // 4096*64 per (b,h)
#define LM_STRIDE 16384     // 256*64
#define MM_STRIDE 65536     // 256*256

__global__ __launch_bounds__(256) void zero_scal(float* scal) {
  if (threadIdx.x < 2) scal[threadIdx.x] = 0.0f;
}

// ---------------- qkv = x @ w_qkv, split to q/k/v [b,h,n,64], q *= 0.125 ----
__global__ __launch_bounds__(256) void gemm_qkv(const float* __restrict__ x,
                                                const float* __restrict__ w,
                                                float* __restrict__ q,
                                                float* __restrict__ k,
                                                float* __restrict__ v) {
  __shared__ float As[16][64];
  __shared__ float Bs[16][64];
  const int tid = threadIdx.x;
  const int bm = blockIdx.x, bn = blockIdx.y;  // 256 x 24
  const int ty = tid >> 4, tx = tid & 15;
  const int ar = tid >> 2, ak = (tid & 3) << 2;
  const int br = tid >> 4, bc = (tid & 15) << 2;
  const float* Ag = x + (size_t)(bm * 64 + ar) * 512 + ak;
  const float* Bg = w + (size_t)br * 1536 + bn * 64 + bc;
  float acc[4][4] = {};
  for (int kt = 0; kt < 32; ++kt) {
    float4 a4 = *(const float4*)(Ag + kt * 16);
    float4 b4 = *(const float4*)(Bg + (size_t)kt * 16 * 1536);
    __syncthreads();
    As[ak + 0][ar] = a4.x; As[ak + 1][ar] = a4.y;
    As[ak + 2][ar] = a4.z; As[ak + 3][ar] = a4.w;
    *(float4*)&Bs[br][bc] = b4;
    __syncthreads();
#pragma unroll
    for (int kk = 0; kk < 16; ++kk) {
      const float4 a = *(const float4*)&As[kk][ty << 2];
      const float4 b = *(const float4*)&Bs[kk][tx << 2];
      acc[0][0] += a.x * b.x; acc[0][1] += a.x * b.y; acc[0][2] += a.x * b.z; acc[0][3] += a.x * b.w;
      acc[1][0] += a.y * b.x; acc[1][1] += a.y * b.y; acc[1][2] += a.y * b.z; acc[1][3] += a.y * b.w;
      acc[2][0] += a.z * b.x; acc[2][1] += a.z * b.y; acc[2][2] += a.z * b.z; acc[2][3] += a.z * b.w;
      acc[3][0] += a.w * b.x; acc[3][1] += a.w * b.y; acc[3][2] += a.w * b.z; acc[3][3] += a.w * b.w;
    }
  }
  const int which = bn >> 3;   // 0:q 1:k 2:v
  const int head = bn & 7;
  float* dst = which == 0 ? q : (which == 1 ? k : v);
  const float scale = which == 0 ? 0.125f : 1.0f;
  const int r0 = bm * 64 + (ty << 2);
  const int b = r0 >> 12;
  const int colb = tx << 2;
#pragma unroll
  for (int i = 0; i < 4; ++i) {
    const int seq = (r0 + i) & 4095;
    float4 o;
    o.x = acc[i][0] * scale; o.y = acc[i][1] * scale;
    o.z = acc[i][2] * scale; o.w = acc[i][3] * scale;
    *(float4*)&dst[(size_t)(b * 8 + head) * QKV_STRIDE + seq * 64 + colb] = o;
  }
}

// ---------------- landmark means: ql,kl [b,h,256,64] ------------------------
__global__ __launch_bounds__(256) void lmk_mean(const float* __restrict__ q,
                                                const float* __restrict__ k,
                                                float* __restrict__ ql,
                                                float* __restrict__ kl) {
  const int g = blockIdx.x * 256 + threadIdx.x;  // 524288
  const int dd = g & 63, mi = (g >> 6) & 255, bh = g >> 14;
  const size_t base = (size_t)bh * QKV_STRIDE + mi * 1024 + dd;
  float sq = 0.f, sk = 0.f;
#pragma unroll
  for (int jj = 0; jj < 16; ++jj) {
    sq += q[base + jj * 64];
    sk += k[base + jj * 64];
  }
  ql[g] = sq * 0.0625f;
  kl[g] = sk * 0.0625f;
}

// ---------------- sim2 = ql @ kl^T, softmax -> x2 [b,h,256,256] -------------
__global__ __launch_bounds__(256) void sim2_softmax(const float* __restrict__ ql,
                                                    const float* __restrict__ kl,
                                                    float* __restrict__ x2) {
  const int blk = blockIdx.x;        // 512 = 32 bh * 16 rowgroups
  const int bh = blk >> 4, rg = blk & 15;
  __shared__ float Qs[16][64];
  __shared__ float Ks[64][68];
  __shared__ float S[16][257];
  __shared__ float red[16][17];
  __shared__ float rowinv[16];
  const int tid = threadIdx.x;
  const int r = tid >> 4, jc = tid & 15;
#pragma unroll
  for (int u = 0; u < 4; ++u) {
    int t2 = tid + u * 256;
    Qs[t2 >> 6][t2 & 63] =
        ql[(size_t)bh * LM_STRIDE + (rg * 16 + (t2 >> 6)) * 64 + (t2 & 63)];
  }
  for (int c = 0; c < 4; ++c) {
    __syncthreads();
#pragma unroll
    for (int u = 0; u < 4; ++u) {
      int t4 = tid + u * 256;
      int row = t4 >> 4, c4 = (t4 & 15) << 2;
      *(float4*)&Ks[row][c4] =
          *(const float4*)&kl[(size_t)bh * LM_STRIDE + (c * 64 + row) * 64 + c4];
    }
    __syncthreads();
#pragma unroll
    for (int s = 0; s < 4; ++s) {
      const int jj = jc + (s << 4);
      float acc = 0.f;
#pragma unroll
      for (int k4 = 0; k4 < 16; ++k4) {
        const float4 a = *(const float4*)&Qs[r][k4 << 2];
        const float4 bb = *(const float4*)&Ks[jj][k4 << 2];
        acc += a.x * bb.x + a.y * bb.y + a.z * bb.z + a.w * bb.w;
      }
      S[r][(c << 6) + jj] = acc;
    }
  }
  __syncthreads();
  float pm = -3.0e38f;
#pragma unroll
  for (int u = 0; u < 16; ++u) pm = fmaxf(pm, S[r][jc + (u << 4)]);
  red[r][jc] = pm;
  __syncthreads();
  float m = red[r][0];
#pragma unroll
  for (int u = 1; u < 16; ++u) m = fmaxf(m, red[r][u]);
  __syncthreads();
  float ps = 0.f;
#pragma unroll
  for (int u = 0; u < 16; ++u) {
    const int j = jc + (u << 4);
    const float e = __expf(S[r][j] - m);
    S[r][j] = e;
    ps += e;
  }
  red[r][jc] = ps;
  __syncthreads();
  if (jc == 0) {
    float sum = 0.f;
#pragma unroll
    for (int u = 0; u < 16; ++u) sum += red[r][u];
    rowinv[r] = 1.0f / sum;
  }
  __syncthreads();
  for (int idx = tid; idx < 4096; idx += 256) {
    const int rr = idx >> 8, j = idx & 255;
    x2[(size_t)bh * MM_STRIDE + (rg * 16 + rr) * 256 + j] = S[rr][j] * rowinv[rr];
  }
}

// ---------------- global max of col-sums / row-sums of |x2| -----------------
__global__ __launch_bounds__(256) void colrow_max(const float* __restrict__ x2,
                                                  float* __restrict__ scal) {
  const int bh = blockIdx.x;
  const int tid = threadIdx.x;
  const float* xb = x2 + (size_t)bh * MM_STRIDE;
  float cs = 0.f, rs = 0.f;
  for (int j = 0; j < 256; ++j) cs += fabsf(xb[tid * 256 + j]);
  for (int i = 0; i < 256; ++i) rs += fabsf(xb[i * 256 + tid]);
  __shared__ float rc[256], rr[256];
  rc[tid] = cs; rr[tid] = rs;
  __syncthreads();
  for (int st = 128; st > 0; st >>= 1) {
    if (tid < st) {
      rc[tid] = fmaxf(rc[tid], rc[tid + st]);
      rr[tid] = fmaxf(rr[tid], rr[tid + st]);
    }
    __syncthreads();
  }
  if (tid == 0) {
    atomicMax((int*)&scal[0], __float_as_int(rc[0]));
    atomicMax((int*)&scal[1], __float_as_int(rr[0]));
  }
}

// ---------------- z0 = x2^T / (cmax*rmax) -----------------------------------
__global__ __launch_bounds__(256) void tscale(const float* __restrict__ x2,
                                              const float* __restrict__ scal,
                                              float* __restrict__ z0) {
  const int g = blockIdx.x * 256 + threadIdx.x;  // 2097152
  const int j = g & 255, i = (g >> 8) & 255, bh = g >> 16;
  const float inv = 1.0f / (scal[0] * scal[1]);
  z0[g] = x2[(size_t)bh * MM_STRIDE + j * 256 + i] * inv;
}

// ---------------- batched 256x256x256: C = alpha*A + beta*(A@B) -------------
__global__ __launch_bounds__(256) void bgemm_pinv(const float* __restrict__ A,
                                                  const float* __restrict__ B,
                                                  float* __restrict__ C,
                                                  float alpha, float beta) {
  const int batch = blockIdx.y;
  const int tm = blockIdx.x >> 2, tn = blockIdx.x & 3;
  const float* Ab = A + (size_t)batch * MM_STRIDE;
  const float* Bb = B + (size_t)batch * MM_STRIDE;
  float* Cb = C + (size_t)batch * MM_STRIDE;
  __shared__ float As[16][64];
  __shared__ float Bs[16][64];
  const int tid = threadIdx.x;
  const int ty = tid >> 4, tx = tid & 15;
  const int ar = tid >> 2, ak = (tid & 3) << 2;
  const int br = tid >> 4, bc = (tid & 15) << 2;
  const float* Ag = Ab + (tm * 64 + ar) * 256 + ak;
  const float* Bg = Bb + br * 256 + tn * 64 + bc;
  float acc[4][4] = {};
  for (int kt = 0; kt < 16; ++kt) {
    float4 a4 = *(const float4*)(Ag + kt * 16);
    float4 b4 = *(const float4*)(Bg + kt * 16 * 256);
    __syncthreads();
    As[ak + 0][ar] = a4.x; As[ak + 1][ar] = a4.y;
    As[ak + 2][ar] = a4.z; As[ak + 3][ar] = a4.w;
    *(float4*)&Bs[br][bc] = b4;
    __syncthreads();
#pragma unroll
    for (int kk = 0; kk < 16; ++kk) {
      const float4 a = *(const float4*)&As[kk][ty << 2];
      const float4 b = *(const float4*)&Bs[kk][tx << 2];
      acc[0][0] += a.x * b.x; acc[0][1] += a.x * b.y; acc[0][2] += a.x * b.z; acc[0][3] += a.x * b.w;
      acc[1][0] += a.y * b.x; acc[1][1] += a.y * b.y; acc[1][2] += a.y * b.z; acc[1][3] += a.y * b.w;
      acc[2][0] += a.z * b.x; acc[2][1] += a.z * b.y; acc[2][2] += a.z * b.z; acc[2][3] += a.z * b.w;
      acc[3][0] += a.w * b.x; acc[3][1] += a.w * b.y; acc[3][2] += a.w * b.z; acc[3][3] += a.w * b.w;
    }
  }
  const int gi0 = tm * 64 + (ty << 2);
  const int gj = tn * 64 + (tx << 2);
#pragma unroll
  for (int i = 0; i < 4; ++i) {
    const float4 a4 = *(const float4*)&Ab[(gi0 + i) * 256 + gj];
    float4 o;
    o.x = alpha * a4.x + beta * acc[i][0];
    o.y = alpha * a4.y + beta * acc[i][1];
    o.z = alpha * a4.z + beta * acc[i][2];
    o.w = alpha * a4.w + beta * acc[i][3];
    *(float4*)&Cb[(gi0 + i) * 256 + gj] = o;
  }
}

// ---------------- attn3 pass A: per-row (m, l) over 4096 keys ---------------
__global__ __launch_bounds__(256) void attn3_ml(const float* __restrict__ ql,
                                                const float* __restrict__ k,
                                                float* __restrict__ marr,
                                                float* __restrict__ larr) {
  const int blk = blockIdx.x;  // 512
  const int bh = blk >> 4, rg = blk & 15;
  __shared__ float Qs[16][64];
  __shared__ float Ks[64][68];
  __shared__ float redm[16][17], redl[16][17];
  const int tid = threadIdx.x;
  const int r = tid >> 4, jc = tid & 15;
#pragma unroll
  for (int u = 0; u < 4; ++u) {
    int t2 = tid + u * 256;
    Qs[t2 >> 6][t2 & 63] =
        ql[(size_t)bh * LM_STRIDE + (rg * 16 + (t2 >> 6)) * 64 + (t2 & 63)];
  }
  float mt = -3.0e38f, lt = 0.f;
  for (int c = 0; c < 64; ++c) {
    __syncthreads();
#pragma unroll
    for (int u = 0; u < 4; ++u) {
      int t4 = tid + u * 256;
      int row = t4 >> 4, c4 = (t4 & 15) << 2;
      *(float4*)&Ks[row][c4] =
          *(const float4*)&k[(size_t)bh * QKV_STRIDE + (c * 64 + row) * 64 + c4];
    }
    __syncthreads();
#pragma unroll
    for (int s = 0; s < 4; ++s) {
      const int jj = jc + (s << 4);
      float acc = 0.f;
#pragma unroll
      for (int k4 = 0; k4 < 16; ++k4) {
        const float4 a = *(const float4*)&Qs[r][k4 << 2];
        const float4 bb = *(const float4*)&Ks[jj][k4 << 2];
        acc += a.x * bb.x + a.y * bb.y + a.z * bb.z + a.w * bb.w;
      }
      if (acc > mt) { lt = lt * __expf(mt - acc) + 1.0f; mt = acc; }
      else lt += __expf(acc - mt);
    }
  }
  redm[r][jc] = mt; redl[r][jc] = lt;
  __syncthreads();
  if (jc == 0) {
    float m = redm[r][0];
#pragma unroll
    for (int u = 1; u < 16; ++u) m = fmaxf(m, redm[r][u]);
    float l = 0.f;
#pragma unroll
    for (int u = 0; u < 16; ++u) l += redl[r][u] * __expf(redm[r][u] - m);
    marr[bh * 256 + rg * 16 + r] = m;
    larr[bh * 256 + rg * 16 + r] = l;
  }
}

// ---------------- attn3 pass B: av = softmax(ql@k^T) @ v --------------------
__global__ __launch_bounds__(256) void attn3_av(const float* __restrict__ ql,
                                                const float* __restrict__ k,
                                                const float* __restrict__ v,
                                                const float* __restrict__ marr,
                                                const float* __restrict__ larr,
                                                float* __restrict__ av) {
  const int blk = blockIdx.x;  // 512
  const int bh = blk >> 4, rg = blk & 15;
  __shared__ float Qs[16][64];
  __shared__ float Ks[64][68];
  __shared__ float Vs[64][68];
  __shared__ float P[16][68];
  __shared__ float mrow[16], linv[16];
  const int tid = threadIdx.x;
  const int r = tid >> 4, jc = tid & 15;
#pragma unroll
  for (int u = 0; u < 4; ++u) {
    int t2 = tid + u * 256;
    Qs[t2 >> 6][t2 & 63] =
        ql[(size_t)bh * LM_STRIDE + (rg * 16 + (t2 >> 6)) * 64 + (t2 & 63)];
  }
  if (tid < 16) {
    mrow[tid] = marr[bh * 256 + rg * 16 + tid];
    linv[tid] = 1.0f / larr[bh * 256 + rg * 16 + tid];
  }
  float o0 = 0.f, o1 = 0.f, o2 = 0.f, o3 = 0.f;
  for (int c = 0; c < 64; ++c) {
    __syncthreads();
#pragma unroll
    for (int u = 0; u < 4; ++u) {
      int t4 = tid + u * 256;
      int row = t4 >> 4, c4 = (t4 & 15) << 2;
      *(float4*)&Ks[row][c4] =
          *(const float4*)&k[(size_t)bh * QKV_STRIDE + (c * 64 + row) * 64 + c4];
      *(float4*)&Vs[row][c4] =
          *(const float4*)&v[(size_t)bh * QKV_STRIDE + (c * 64 + row) * 64 + c4];
    }
    __syncthreads();
#pragma unroll
    for (int s = 0; s < 4; ++s) {
      const int jj = jc + (s << 4);
      float acc = 0.f;
#pragma unroll
      for (int k4 = 0; k4 < 16; ++k4) {
        const float4 a = *(const float4*)&Qs[r][k4 << 2];
        const float4 bb = *(const float4*)&Ks[jj][k4 << 2];
        acc += a.x * bb.x + a.y * bb.y + a.z * bb.z + a.w * bb.w;
      }
      P[r][jj] = __expf(acc - mrow[r]) * linv[r];
    }
    __syncthreads();
#pragma unroll
    for (int j = 0; j < 64; ++j) {
      const float p = P[r][j];
      const float4 vv = *(const float4*)&Vs[j][jc << 2];
      o0 += p * vv.x; o1 += p * vv.y; o2 += p * vv.z; o3 += p * vv.w;
    }
  }
  float4 o = make_float4(o0, o1, o2, o3);
  *(float4*)&av[(size_t)bh * LM_STRIDE + (rg * 16 + r) * 64 + (jc << 2)] = o;
}

// ---------------- w2 = z_final @ av : [256,256]@[256,64] per bh -------------
__global__ __launch_bounds__(256) void zav_gemm(const float* __restrict__ z,
                                                const float* __restrict__ av,
                                                float* __restrict__ w2) {
  const int bh = blockIdx.x;
  const int rq = blockIdx.y;  // 0..3
  __shared__ float Av[256][64];
  const int tid = threadIdx.x;
#pragma unroll
  for (int u = 0; u < 16; ++u) {
    int t4 = tid + u * 256;
    int row = t4 >> 4, c4 = (t4 & 15) << 2;
    *(float4*)&Av[row][c4] = *(const float4*)&av[(size_t)bh * LM_STRIDE + row * 64 + c4];
  }
  __syncthreads();
  const int d = tid & 63, rg4 = tid >> 6;
  for (int s = 0; s < 16; ++s) {
    const int i = rq * 64 + s * 4 + rg4;
    const float* zr = z + (size_t)bh * MM_STRIDE + i * 256;
    float acc = 0.f;
#pragma unroll 8
    for (int j = 0; j < 256; ++j) acc += zr[j] * Av[j][d];
    w2[(size_t)bh * LM_STRIDE + i * 64 + d] = acc;
  }
}

// ---------------- out_heads = softmax(q@kl^T) @ w2 (in-place over q) --------
__global__ __launch_bounds__(256) void attn1_fused(const float* __restrict__ q,
                                                   const float* __restrict__ kl,
                                                   const float* __restrict__ w2,
                                                   float* __restrict__ oh) {
  const int blk = blockIdx.x;  // 8192 = 32 bh * 256 rowgroups
  const int bh = blk >> 8, rg = blk & 255;
  __shared__ float Qs[16][64];
  __shared__ float Ks[64][68];
  __shared__ float S[16][257];
  __shared__ float red[16][17];
  const int tid = threadIdx.x;
  const int r = tid >> 4, jc = tid & 15;
#pragma unroll
  for (int u = 0; u < 4; ++u) {
    int t2 = tid + u * 256;
    Qs[t2 >> 6][t2 & 63] =
        q[(size_t)bh * QKV_STRIDE + (rg * 16 + (t2 >> 6)) * 64 + (t2 & 63)];
  }
  for (int c = 0; c < 4; ++c) {
    __syncthreads();
#pragma unroll
    for (int u = 0; u < 4; ++u) {
      int t4 = tid + u * 256;
      int row = t4 >> 4, c4 = (t4 & 15) << 2;
      *(float4*)&Ks[row][c4] =
          *(const float4*)&kl[(size_t)bh * LM_STRIDE + (c * 64 + row) * 64 + c4];
    }
    __syncthreads();
#pragma unroll
    for (int s = 0; s < 4; ++s) {
      const int jj = jc + (s << 4);
      float acc = 0.f;
#pragma unroll
      for (int k4 = 0; k4 < 16; ++k4) {
        const float4 a = *(const float4*)&Qs[r][k4 << 2];
        const float4 bb = *(const float4*)&Ks[jj][k4 << 2];
        acc += a.x * bb.x + a.y * bb.y + a.z * bb.z + a.w * bb.w;
      }
      S[r][(c << 6) + jj] = acc;
    }
  }
  __syncthreads();
  float pm = -3.0e38f;
#pragma unroll
  for (int u = 0; u < 16; ++u) pm = fmaxf(pm, S[r][jc + (u << 4)]);
  red[r][jc] = pm;
  __syncthreads();
  float m = red[r][0];
#pragma unroll
  for (int u = 1; u < 16; ++u) m = fmaxf(m, red[r][u]);
  __syncthreads();
  float ps = 0.f;
#pragma unroll
  for (int u = 0; u < 16; ++u) {
    const int j = jc + (u << 4);
    const float e = __expf(S[r][j] - m);
    S[r][j] = e;
    ps += e;
  }
  red[r][jc] = ps;
  __syncthreads();
  float sum = 0.f;
#pragma unroll
  for (int u = 0; u < 16; ++u) sum += red[r][u];
  const float inv = 1.0f / sum;
#pragma unroll
  for (int u = 0; u < 16; ++u) S[r][jc + (u << 4)] *= inv;
  // P @ w2
  float o0 = 0.f, o1 = 0.f, o2 = 0.f, o3 = 0.f;
  for (int c = 0; c < 4; ++c) {
    __syncthreads();
#pragma unroll
    for (int u = 0; u < 4; ++u) {
      int t4 = tid + u * 256;
      int row = t4 >> 4, c4 = (t4 & 15) << 2;
      *(float4*)&Ks[row][c4] =
          *(const float4*)&w2[(size_t)bh * LM_STRIDE + (c * 64 + row) * 64 + c4];
    }
    __syncthreads();
#pragma unroll
    for (int j = 0; j < 64; ++j) {
      const float p = S[r][(c << 6) + j];
      const float4 wv = *(const float4*)&Ks[j][jc << 2];
      o0 += p * wv.x; o1 += p * wv.y; o2 += p * wv.z; o3 += p * wv.w;
    }
  }
  float4 o = make_float4(o0, o1, o2, o3);
  *(float4*)&oh[(size_t)bh * QKV_STRIDE + (rg * 16 + r) * 64 + (jc << 2)] = o;
}

// ---------------- depthwise conv residual: oh += conv(v) --------------------
__global__ __launch_bounds__(256) void conv_res(const float* __restrict__ v,
                                                const float* __restrict__ cw,
                                                float* __restrict__ oh) {
  const int g = blockIdx.x * 256 + threadIdx.x;  // 8388608
  const int dd = g & 63, i = (g >> 6) & 4095, bh = g >> 18;
  const int h = bh & 7;
  float acc = oh[g];
  const size_t base = (size_t)bh * QKV_STRIDE + dd;
#pragma unroll
  for (int t = 0; t < 33; ++t) {
    const int si = i + t - 16;
    if (si >= 0 && si < 4096) acc += cw[h * 33 + t] * v[base + (size_t)si * 64];
  }
  oh[g] = acc;
}

// ---------------- out = concat_heads(oh) @ w_out + b_out --------------------
__global__ __launch_bounds__(256) void gemm_out(const float* __restrict__ oh,
                                                const float* __restrict__ w,
                                                const float* __restrict__ bias,
                                                float* __restrict__ out) {
  __shared__ float As[16][64];
  __shared__ float Bs[16][64];
  const int tid = threadIdx.x;
  const int bm = blockIdx.x, bn = blockIdx.y;  // 256 x 8
  const int ty = tid >> 4, tx = tid & 15;
  const int ar = tid >> 2, ak = (tid & 3) << 2;
  const int br = tid >> 4, bc = (tid & 15) << 2;
  const int r = bm * 64 + ar;
  const int b = r >> 12, seq = r & 4095;
  float acc[4][4] = {};
  for (int kt = 0; kt < 32; ++kt) {
    const int kk0 = kt * 16 + ak;
    const int h = kk0 >> 6, dd = kk0 & 63;
    float4 a4 = *(const float4*)&oh[(size_t)(b * 8 + h) * QKV_STRIDE + seq * 64 + dd];
    float4 b4 = *(const float4*)&w[(size_t)(kt * 16 + br) * 512 + bn * 64 + bc];
    __syncthreads();
    As[ak + 0][ar] = a4.x; As[ak + 1][ar] = a4.y;
    As[ak + 2][ar] = a4.z; As[ak + 3][ar] = a4.w;
    *(float4*)&Bs[br][bc] = b4;
    __syncthreads();
#pragma unroll
    for (int kk = 0; kk < 16; ++kk) {
      const float4 a = *(const float4*)&As[kk][ty << 2];
      const float4 bb = *(const float4*)&Bs[kk][tx << 2];
      acc[0][0] += a.x * bb.x; acc[0][1] += a.x * bb.y; acc[0][2] += a.x * bb.z; acc[0][3] += a.x * bb.w;
      acc[1][0] += a.y * bb.x; acc[1][1] += a.y * bb.y; acc[1][2] += a.y * bb.z; acc[1][3] += a.y * bb.w;
      acc[2][0] += a.z * bb.x; acc[2][1] += a.z * bb.y; acc[2][2] += a.z * bb.z; acc[2][3] += a.z * bb.w;
      acc[3][0] += a.w * bb.x; acc[3][1] += a.w * bb.y; acc[3][2] += a.w * bb.z; acc[3][3] += a.w * bb.w;
    }
  }
  const int c0 = bn * 64 + (tx << 2);
  const float4 bb4 = *(const float4*)&bias[c0];
  const int r0 = bm * 64 + (ty << 2);
#pragma unroll
  for (int i = 0; i < 4; ++i) {
    float4 o;
    o.x = acc[i][0] + bb4.x; o.y = acc[i][1] + bb4.y;
    o.z = acc[i][2] + bb4.z; o.w = acc[i][3] + bb4.w;
    *(float4*)&out[(size_t)(r0 + i) * 512 + c0] = o;
  }
}

// ---------------------------------------------------------------------------
extern "C" void kernel_launch(void* const* d_in, const int* in_sizes, int n_in,
                              void* d_out, int out_size, void* d_ws, size_t ws_size,
                              hipStream_t stream) {
  const float* x    = (const float*)d_in[0];
  const float* wqkv = (const float*)d_in[1];
  const float* wout = (const float*)d_in[2];
  const float* bout = (const float*)d_in[3];
  const float* cw   = (const float*)d_in[4];
  float* out = (float*)d_out;

  float* w = (float*)d_ws;
  float* q    = w;                    // [4,8,4096,64]; reused as out_heads
  float* k    = w + 8388608;
  float* v    = w + 16777216;
  float* ql   = w + 25165824;         // [4,8,256,64]
  float* kl   = ql + 524288;
  float* x2   = kl + 524288;          // attn2 [4,8,256,256]
  float* z0   = x2 + 2097152;
  float* z1   = z0 + 2097152;
  float* xz   = z1 + 2097152;
  float* t1   = xz + 2097152;
  float* t2   = t1 + 2097152;
  float* av   = t2 + 2097152;         // [4,8,256,64]
  float* w2   = av + 524288;
  float* marr = w2 + 524288;          // [32,256]
  float* larr = marr + 8192;
  float* scal = larr + 8192;          // [2]

  zero_scal<<<1, 64, 0, stream>>>(scal);
  gemm_qkv<<<dim3(256, 24), 256, 0, stream>>>(x, wqkv, q, k, v);
  lmk_mean<<<2048, 256, 0, stream>>>(q, k, ql, kl);
  sim2_softmax<<<512, 256, 0, stream>>>(ql, kl, x2);
  colrow_max<<<32, 256, 0, stream>>>(x2, scal);
  tscale<<<8192, 256, 0, stream>>>(x2, scal, z0);

  float* zc = z0;
  float* zn = z1;
  for (int it = 0; it < 6; ++it) {
    bgemm_pinv<<<dim3(16, 32), 256, 0, stream>>>(x2, zc, xz, 0.0f, 1.0f);
    bgemm_pinv<<<dim3(16, 32), 256, 0, stream>>>(xz, xz, t1, 7.0f, -1.0f);
    bgemm_pinv<<<dim3(16, 32), 256, 0, stream>>>(xz, t1, t2, 15.0f, -1.0f);
    bgemm_pinv<<<dim3(16, 32), 256, 0, stream>>>(zc, t2, zn, 3.25f, -0.25f);
    float* tmp = zc; zc = zn; zn = tmp;
  }

  attn3_ml<<<512, 256, 0, stream>>>(ql, k, marr, larr);
  attn3_av<<<512, 256, 0, stream>>>(ql, k, v, marr, larr, av);
  zav_gemm<<<dim3(32, 4), 256, 0, stream>>>(zc, av, w2);
  attn1_fused<<<8192, 256, 0, stream>>>(q, kl, w2, q /* in-place */);
  conv_res<<<32768, 256, 0, stream>>>(v, cw, q);
  gemm_out<<<dim3(256, 8), 256, 0, stream>>>(q, wout, bout, out);
}

// Round 2
// 1701.178 us; speedup vs baseline: 1.3593x; 1.3593x over previous
//
#include <hip/hip_runtime.h>
#include <math.h>

// ---------------------------------------------------------------------------
// NystromAttention round 2: MFMA-bf16 for qkv/out/attn1, split-bf16 MFMA pinv.
// b=4 n=4096 dim=512 h=8 d=64 m=256, l=16, iters=6, conv k=33.
// MFMA 16x16x32_bf16 layouts (HW-verified per guide):
//   A: m=lane&15, k=(lane>>4)*8+j    B: n=lane&15, k=(lane>>4)*8+j
//   C/D: col=lane&15, row=(lane>>4)*4+reg
// ---------------------------------------------------------------------------

#define QKV_STRIDE 262144   // 4096*64 per (b,h)
#define LM_STRIDE 16384     // 256*64
#define MM_STRIDE 65536     // 256*256

typedef float f32x4 __attribute__((ext_vector_type(4)));
typedef short bf8 __attribute__((ext_vector_type(8)));   // 8 bf16 in 4 VGPRs
typedef short s4v __attribute__((ext_vector_type(4)));

__device__ __forceinline__ unsigned short f2bf_(float f) {
  unsigned u = __float_as_uint(f);
  u += 0x7FFFu + ((u >> 16) & 1u);   // RNE
  return (unsigned short)(u >> 16);
}
__device__ __forceinline__ float bf2f_(unsigned short h) {
  return __uint_as_float(((unsigned)h) << 16);
}
__device__ __forceinline__ bf8 pack8(const float4 a, const float4 b) {
  bf8 r;
  r[0] = (short)f2bf_(a.x); r[1] = (short)f2bf_(a.y);
  r[2] = (short)f2bf_(a.z); r[3] = (short)f2bf_(a.w);
  r[4] = (short)f2bf_(b.x); r[5] = (short)f2bf_(b.y);
  r[6] = (short)f2bf_(b.z); r[7] = (short)f2bf_(b.w);
  return r;
}

__global__ __launch_bounds__(256) void zero_scal(float* scal) {
  if (threadIdx.x < 2) scal[threadIdx.x] = 0.0f;
}

// ------------- transpose + fp32->bf16: dst[C][R] = bf16(src[R][C]) ----------
__global__ __launch_bounds__(256) void transpose_bf16(const float* __restrict__ src,
                                                      short* __restrict__ dst,
                                                      int R, int C) {
  __shared__ float T[32][33];
  const int t = threadIdx.x;
  const int c0 = blockIdx.x * 32, r0 = blockIdx.y * 32;
  const int tr = t >> 3, tc = (t & 7) << 2;
  float4 vsrc = *(const float4*)&src[(size_t)(r0 + tr) * C + c0 + tc];
  T[tr][tc + 0] = vsrc.x; T[tr][tc + 1] = vsrc.y;
  T[tr][tc + 2] = vsrc.z; T[tr][tc + 3] = vsrc.w;
  __syncthreads();
  s4v o;
  o[0] = (short)f2bf_(T[tc + 0][tr]);
  o[1] = (short)f2bf_(T[tc + 1][tr]);
  o[2] = (short)f2bf_(T[tc + 2][tr]);
  o[3] = (short)f2bf_(T[tc + 3][tr]);
  *(s4v*)&dst[(size_t)(c0 + tr) * R + r0 + tc] = o;
}

// ------------- qkv = x @ w_qkv via MFMA; scatter to q/k/v, q*=0.125 ---------
__global__ __launch_bounds__(256) void gemm_qkv_mfma(const float* __restrict__ x,
                                                     const short* __restrict__ wT,
                                                     float* __restrict__ q,
                                                     float* __restrict__ k,
                                                     float* __restrict__ v) {
  __shared__ short As[4096];  // 128x32 frag-order
  __shared__ short Bs[4096];
  const int tid = threadIdx.x;
  const int lane = tid & 63, w = tid >> 6;
  const int wr = w >> 1, wc = w & 1;
  const int gm0 = blockIdx.x * 128, gn0 = blockIdx.y * 128;
  // staging slots: s and s+256; slot s -> mb=s>>6, l=s&63
  const int mA0 = (tid >> 6) * 16 + (tid & 15), kA0 = ((tid >> 4) & 3) * 8;
  const int s1 = tid + 256;
  const int mA1 = (s1 >> 6) * 16 + (s1 & 15), kA1 = ((s1 >> 4) & 3) * 8;
  f32x4 acc[4][4];
#pragma unroll
  for (int i = 0; i < 4; ++i)
#pragma unroll
    for (int j = 0; j < 4; ++j) acc[i][j] = (f32x4){0.f, 0.f, 0.f, 0.f};
  for (int kt = 0; kt < 16; ++kt) {
    const int k0 = kt * 32;
    float4 a0 = *(const float4*)&x[(size_t)(gm0 + mA0) * 512 + k0 + kA0];
    float4 a1 = *(const float4*)&x[(size_t)(gm0 + mA0) * 512 + k0 + kA0 + 4];
    float4 a2 = *(const float4*)&x[(size_t)(gm0 + mA1) * 512 + k0 + kA1];
    float4 a3 = *(const float4*)&x[(size_t)(gm0 + mA1) * 512 + k0 + kA1 + 4];
    bf8 b0 = *(const bf8*)&wT[(size_t)(gn0 + mA0) * 512 + k0 + kA0];
    bf8 b1 = *(const bf8*)&wT[(size_t)(gn0 + mA1) * 512 + k0 + kA1];
    __syncthreads();
    *(bf8*)&As[tid * 8] = pack8(a0, a1);
    *(bf8*)&As[s1 * 8] = pack8(a2, a3);
    *(bf8*)&Bs[tid * 8] = b0;
    *(bf8*)&Bs[s1 * 8] = b1;
    __syncthreads();
    bf8 af[4], bf[4];
#pragma unroll
    for (int i = 0; i < 4; ++i) {
      af[i] = *(const bf8*)&As[((wr * 4 + i) * 64 + lane) * 8];
      bf[i] = *(const bf8*)&Bs[((wc * 4 + i) * 64 + lane) * 8];
    }
#pragma unroll
    for (int i = 0; i < 4; ++i)
#pragma unroll
      for (int j = 0; j < 4; ++j)
        acc[i][j] = __builtin_amdgcn_mfma_f32_16x16x32_bf16(af[i], bf[j], acc[i][j], 0, 0, 0);
  }
  const int which = blockIdx.y >> 2;  // 0:q 1:k 2:v (128 | 512)
  float* dst = which == 0 ? q : (which == 1 ? k : v);
  const float scale = which == 0 ? 0.125f : 1.0f;
  const int qd = lane >> 4, c = lane & 15;
#pragma unroll
  for (int i = 0; i < 4; ++i) {
#pragma unroll
    for (int j = 0; j < 4; ++j) {
      const int col = gn0 + wc * 64 + j * 16 + c;  // within [0,1536)
      const int head = (col >> 6) & 7, dd = col & 63;
#pragma unroll
      for (int r = 0; r < 4; ++r) {
        const int row = gm0 + wr * 64 + i * 16 + qd * 4 + r;
        const int b = row >> 12, seq = row & 4095;
        dst[(size_t)(b * 8 + head) * QKV_STRIDE + seq * 64 + dd] = acc[i][j][r] * scale;
      }
    }
  }
}

// ---------------- landmark means ------------------------------------------
__global__ __launch_bounds__(256) void lmk_mean(const float* __restrict__ q,
                                                const float* __restrict__ k,
                                                float* __restrict__ ql,
                                                float* __restrict__ kl) {
  const int g = blockIdx.x * 256 + threadIdx.x;
  const int dd = g & 63, mi = (g >> 6) & 255, bh = g >> 14;
  const size_t base = (size_t)bh * QKV_STRIDE + mi * 1024 + dd;
  float sq = 0.f, sk = 0.f;
#pragma unroll
  for (int jj = 0; jj < 16; ++jj) {
    sq += q[base + jj * 64];
    sk += k[base + jj * 64];
  }
  ql[g] = sq * 0.0625f;
  kl[g] = sk * 0.0625f;
}

// ---------------- sim2 = ql @ kl^T, softmax -> x2 ---------------------------
__global__ __launch_bounds__(256) void sim2_softmax(const float* __restrict__ ql,
                                                    const float* __restrict__ kl,
                                                    float* __restrict__ x2) {
  const int blk = blockIdx.x;
  const int bh = blk >> 4, rg = blk & 15;
  __shared__ float Qs[16][64];
  __shared__ float Ks[64][68];
  __shared__ float S[16][257];
  __shared__ float red[16][17];
  __shared__ float rowinv[16];
  const int tid = threadIdx.x;
  const int r = tid >> 4, jc = tid & 15;
#pragma unroll
  for (int u = 0; u < 4; ++u) {
    int t2 = tid + u * 256;
    Qs[t2 >> 6][t2 & 63] =
        ql[(size_t)bh * LM_STRIDE + (rg * 16 + (t2 >> 6)) * 64 + (t2 & 63)];
  }
  for (int c = 0; c < 4; ++c) {
    __syncthreads();
#pragma unroll
    for (int u = 0; u < 4; ++u) {
      int t4 = tid + u * 256;
      int row = t4 >> 4, c4 = (t4 & 15) << 2;
      *(float4*)&Ks[row][c4] =
          *(const float4*)&kl[(size_t)bh * LM_STRIDE + (c * 64 + row) * 64 + c4];
    }
    __syncthreads();
#pragma unroll
    for (int s = 0; s < 4; ++s) {
      const int jj = jc + (s << 4);
      float acc = 0.f;
#pragma unroll
      for (int k4 = 0; k4 < 16; ++k4) {
        const float4 a = *(const float4*)&Qs[r][k4 << 2];
        const float4 bb = *(const float4*)&Ks[jj][k4 << 2];
        acc += a.x * bb.x + a.y * bb.y + a.z * bb.z + a.w * bb.w;
      }
      S[r][(c << 6) + jj] = acc;
    }
  }
  __syncthreads();
  float pm = -3.0e38f;
#pragma unroll
  for (int u = 0; u < 16; ++u) pm = fmaxf(pm, S[r][jc + (u << 4)]);
  red[r][jc] = pm;
  __syncthreads();
  float m = red[r][0];
#pragma unroll
  for (int u = 1; u < 16; ++u) m = fmaxf(m, red[r][u]);
  __syncthreads();
  float ps = 0.f;
#pragma unroll
  for (int u = 0; u < 16; ++u) {
    const int j = jc + (u << 4);
    const float e = __expf(S[r][j] - m);
    S[r][j] = e;
    ps += e;
  }
  red[r][jc] = ps;
  __syncthreads();
  if (jc == 0) {
    float sum = 0.f;
#pragma unroll
    for (int u = 0; u < 16; ++u) sum += red[r][u];
    rowinv[r] = 1.0f / sum;
  }
  __syncthreads();
  for (int idx = tid; idx < 4096; idx += 256) {
    const int rr = idx >> 8, j = idx & 255;
    x2[(size_t)bh * MM_STRIDE + (rg * 16 + rr) * 256 + j] = S[rr][j] * rowinv[rr];
  }
}

// ---------------- global max of col/row abs-sums ----------------------------
__global__ __launch_bounds__(256) void colrow_max(const float* __restrict__ x2,
                                                  float* __restrict__ scal) {
  const int bh = blockIdx.x;
  const int tid = threadIdx.x;
  const float* xb = x2 + (size_t)bh * MM_STRIDE;
  float cs = 0.f, rs = 0.f;
  for (int j = 0; j < 256; ++j) cs += fabsf(xb[tid * 256 + j]);
  for (int i = 0; i < 256; ++i) rs += fabsf(xb[i * 256 + tid]);
  __shared__ float rc[256], rr[256];
  rc[tid] = cs; rr[tid] = rs;
  __syncthreads();
  for (int st = 128; st > 0; st >>= 1) {
    if (tid < st) {
      rc[tid] = fmaxf(rc[tid], rc[tid + st]);
      rr[tid] = fmaxf(rr[tid], rr[tid + st]);
    }
    __syncthreads();
  }
  if (tid == 0) {
    atomicMax((int*)&scal[0], __float_as_int(rc[0]));
    atomicMax((int*)&scal[1], __float_as_int(rr[0]));
  }
}

// --------- z0 = x2^T/(cmax*rmax), z0t = x2/(cmax*rmax) ----------------------
__global__ __launch_bounds__(256) void tscale2(const float* __restrict__ x2,
                                               const float* __restrict__ scal,
                                               float* __restrict__ z0,
                                               float* __restrict__ z0t) {
  const int g = blockIdx.x * 256 + threadIdx.x;
  const int j = g & 255, i = (g >> 8) & 255, bh = g >> 16;
  const float inv = 1.0f / (scal[0] * scal[1]);
  const float val = x2[g] * inv;      // x2[bh][i][j]
  z0t[g] = val;
  z0[(size_t)bh * MM_STRIDE + j * 256 + i] = val;
}

// --------- split-bf16 batched 256^3: C = alpha*E + beta*(A@B) ---------------
// B supplied transposed (BT[n][k]).  Optionally writes C and/or C^T.
__global__ __launch_bounds__(256) void pinv_mfma(const float* __restrict__ A,
                                                 const float* __restrict__ BT,
                                                 const float* __restrict__ E,
                                                 float* __restrict__ C,
                                                 float* __restrict__ CT,
                                                 float alpha, float beta,
                                                 int wantC, int wantT) {
  __shared__ short Ahi[2048], Alo[2048], Bhi[2048], Blo[2048];  // 64x32 each
  const int tid = threadIdx.x;
  const int lane = tid & 63, w = tid >> 6;
  const int batch = blockIdx.y;
  const int tm = blockIdx.x >> 2, tn = blockIdx.x & 3;
  const float* Ab = A + (size_t)batch * MM_STRIDE;
  const float* BTb = BT + (size_t)batch * MM_STRIDE;
  const float* Eb = E + (size_t)batch * MM_STRIDE;
  const int ml = (tid >> 6) * 16 + (tid & 15), koff = ((tid >> 4) & 3) * 8;
  f32x4 acc[4];
#pragma unroll
  for (int j = 0; j < 4; ++j) acc[j] = (f32x4){0.f, 0.f, 0.f, 0.f};
  for (int kt = 0; kt < 8; ++kt) {
    const int k0 = kt * 32;
    float4 a0 = *(const float4*)&Ab[(size_t)(tm * 64 + ml) * 256 + k0 + koff];
    float4 a1 = *(const float4*)&Ab[(size_t)(tm * 64 + ml) * 256 + k0 + koff + 4];
    float4 b0 = *(const float4*)&BTb[(size_t)(tn * 64 + ml) * 256 + k0 + koff];
    float4 b1 = *(const float4*)&BTb[(size_t)(tn * 64 + ml) * 256 + k0 + koff + 4];
    __syncthreads();
    {
      bf8 hi, lo;
      const float fa[8] = {a0.x, a0.y, a0.z, a0.w, a1.x, a1.y, a1.z, a1.w};
#pragma unroll
      for (int e = 0; e < 8; ++e) {
        unsigned short h = f2bf_(fa[e]);
        hi[e] = (short)h;
        lo[e] = (short)f2bf_(fa[e] - bf2f_(h));
      }
      *(bf8*)&Ahi[tid * 8] = hi;
      *(bf8*)&Alo[tid * 8] = lo;
      const float fb[8] = {b0.x, b0.y, b0.z, b0.w, b1.x, b1.y, b1.z, b1.w};
#pragma unroll
      for (int e = 0; e < 8; ++e) {
        unsigned short h = f2bf_(fb[e]);
        hi[e] = (short)h;
        lo[e] = (short)f2bf_(fb[e] - bf2f_(h));
      }
      *(bf8*)&Bhi[tid * 8] = hi;
      *(bf8*)&Blo[tid * 8] = lo;
    }
    __syncthreads();
    bf8 ah = *(const bf8*)&Ahi[(w * 64 + lane) * 8];
    bf8 al = *(const bf8*)&Alo[(w * 64 + lane) * 8];
#pragma unroll
    for (int j = 0; j < 4; ++j) {
      bf8 bh = *(const bf8*)&Bhi[(j * 64 + lane) * 8];
      bf8 bl = *(const bf8*)&Blo[(j * 64 + lane) * 8];
      acc[j] = __builtin_amdgcn_mfma_f32_16x16x32_bf16(ah, bh, acc[j], 0, 0, 0);
      acc[j] = __builtin_amdgcn_mfma_f32_16x16x32_bf16(ah, bl, acc[j], 0, 0, 0);
      acc[j] = __builtin_amdgcn_mfma_f32_16x16x32_bf16(al, bh, acc[j], 0, 0, 0);
    }
  }
  float* Cb = C + (size_t)batch * MM_STRIDE;
  float* CTb = CT + (size_t)batch * MM_STRIDE;
  const int qd = lane >> 4, c = lane & 15;
#pragma unroll
  for (int j = 0; j < 4; ++j) {
    const int col = tn * 64 + j * 16 + c;
#pragma unroll
    for (int r = 0; r < 4; ++r) {
      const int row = tm * 64 + w * 16 + qd * 4 + r;
      const float val = alpha * Eb[(size_t)row * 256 + col] + beta * acc[j][r];
      if (wantC) Cb[(size_t)row * 256 + col] = val;
      if (wantT) CTb[(size_t)col * 256 + row] = val;
    }
  }
}

// ---------------- attn3 pass A: per-row (m, l) over 4096 keys ---------------
__global__ __launch_bounds__(256) void attn3_ml(const float* __restrict__ ql,
                                                const float* __restrict__ k,
                                                float* __restrict__ marr,
                                                float* __restrict__ larr) {
  const int blk = blockIdx.x;
  const int bh = blk >> 4, rg = blk & 15;
  __shared__ float Qs[16][64];
  __shared__ float Ks[64][68];
  __shared__ float redm[16][17], redl[16][17];
  const int tid = threadIdx.x;
  const int r = tid >> 4, jc = tid & 15;
#pragma unroll
  for (int u = 0; u < 4; ++u) {
    int t2 = tid + u * 256;
    Qs[t2 >> 6][t2 & 63] =
        ql[(size_t)bh * LM_STRIDE + (rg * 16 + (t2 >> 6)) * 64 + (t2 & 63)];
  }
  float mt = -3.0e38f, lt = 0.f;
  for (int c = 0; c < 64; ++c) {
    __syncthreads();
#pragma unroll
    for (int u = 0; u < 4; ++u) {
      int t4 = tid + u * 256;
      int row = t4 >> 4, c4 = (t4 & 15) << 2;
      *(float4*)&Ks[row][c4] =
          *(const float4*)&k[(size_t)bh * QKV_STRIDE + (c * 64 + row) * 64 + c4];
    }
    __syncthreads();
#pragma unroll
    for (int s = 0; s < 4; ++s) {
      const int jj = jc + (s << 4);
      float acc = 0.f;
#pragma unroll
      for (int k4 = 0; k4 < 16; ++k4) {
        const float4 a = *(const float4*)&Qs[r][k4 << 2];
        const float4 bb = *(const float4*)&Ks[jj][k4 << 2];
        acc += a.x * bb.x + a.y * bb.y + a.z * bb.z + a.w * bb.w;
      }
      if (acc > mt) { lt = lt * __expf(mt - acc) + 1.0f; mt = acc; }
      else lt += __expf(acc - mt);
    }
  }
  redm[r][jc] = mt; redl[r][jc] = lt;
  __syncthreads();
  if (jc == 0) {
    float m = redm[r][0];
#pragma unroll
    for (int u = 1; u < 16; ++u) m = fmaxf(m, redm[r][u]);
    float l = 0.f;
#pragma unroll
    for (int u = 0; u < 16; ++u) l += redl[r][u] * __expf(redm[r][u] - m);
    marr[bh * 256 + rg * 16 + r] = m;
    larr[bh * 256 + rg * 16 + r] = l;
  }
}

// ---------------- attn3 pass B: av = softmax(ql@k^T) @ v --------------------
__global__ __launch_bounds__(256) void attn3_av(const float* __restrict__ ql,
                                                const float* __restrict__ k,
                                                const float* __restrict__ v,
                                                const float* __restrict__ marr,
                                                const float* __restrict__ larr,
                                                float* __restrict__ av) {
  const int blk = blockIdx.x;
  const int bh = blk >> 4, rg = blk & 15;
  __shared__ float Qs[16][64];
  __shared__ float Ks[64][68];
  __shared__ float Vs[64][68];
  __shared__ float P[16][68];
  __shared__ float mrow[16], linv[16];
  const int tid = threadIdx.x;
  const int r = tid >> 4, jc = tid & 15;
#pragma unroll
  for (int u = 0; u < 4; ++u) {
    int t2 = tid + u * 256;
    Qs[t2 >> 6][t2 & 63] =
        ql[(size_t)bh * LM_STRIDE + (rg * 16 + (t2 >> 6)) * 64 + (t2 & 63)];
  }
  if (tid < 16) {
    mrow[tid] = marr[bh * 256 + rg * 16 + tid];
    linv[tid] = 1.0f / larr[bh * 256 + rg * 16 + tid];
  }
  float o0 = 0.f, o1 = 0.f, o2 = 0.f, o3 = 0.f;
  for (int c = 0; c < 64; ++c) {
    __syncthreads();
#pragma unroll
    for (int u = 0; u < 4; ++u) {
      int t4 = tid + u * 256;
      int row = t4 >> 4, c4 = (t4 & 15) << 2;
      *(float4*)&Ks[row][c4] =
          *(const float4*)&k[(size_t)bh * QKV_STRIDE + (c * 64 + row) * 64 + c4];
      *(float4*)&Vs[row][c4] =
          *(const float4*)&v[(size_t)bh * QKV_STRIDE + (c * 64 + row) * 64 + c4];
    }
    __syncthreads();
#pragma unroll
    for (int s = 0; s < 4; ++s) {
      const int jj = jc + (s << 4);
      float acc = 0.f;
#pragma unroll
      for (int k4 = 0; k4 < 16; ++k4) {
        const float4 a = *(const float4*)&Qs[r][k4 << 2];
        const float4 bb = *(const float4*)&Ks[jj][k4 << 2];
        acc += a.x * bb.x + a.y * bb.y + a.z * bb.z + a.w * bb.w;
      }
      P[r][jj] = __expf(acc - mrow[r]) * linv[r];
    }
    __syncthreads();
#pragma unroll
    for (int j = 0; j < 64; ++j) {
      const float p = P[r][j];
      const float4 vv = *(const float4*)&Vs[j][jc << 2];
      o0 += p * vv.x; o1 += p * vv.y; o2 += p * vv.z; o3 += p * vv.w;
    }
  }
  float4 o = make_float4(o0, o1, o2, o3);
  *(float4*)&av[(size_t)bh * LM_STRIDE + (rg * 16 + r) * 64 + (jc << 2)] = o;
}

// ---------------- w2^T = (z_final @ av)^T : stores w2t[d][i] ----------------
__global__ __launch_bounds__(256) void zav_gemm_t(const float* __restrict__ z,
                                                  const float* __restrict__ av,
                                                  float* __restrict__ w2t) {
  const int bh = blockIdx.x;
  const int rq = blockIdx.y;
  __shared__ float Av[256][64];
  const int tid = threadIdx.x;
#pragma unroll
  for (int u = 0; u < 16; ++u) {
    int t4 = tid + u * 256;
    int row = t4 >> 4, c4 = (t4 & 15) << 2;
    *(float4*)&Av[row][c4] = *(const float4*)&av[(size_t)bh * LM_STRIDE + row * 64 + c4];
  }
  __syncthreads();
  const int d = tid & 63, rg4 = tid >> 6;
  for (int s = 0; s < 16; ++s) {
    const int i = rq * 64 + s * 4 + rg4;
    const float* zr = z + (size_t)bh * MM_STRIDE + i * 256;
    float acc = 0.f;
#pragma unroll 8
    for (int j = 0; j < 256; ++j) acc += zr[j] * Av[j][d];
    w2t[(size_t)bh * LM_STRIDE + d * 256 + i] = acc;
  }
}

// -------- attn1: oh = softmax(q@kl^T) @ w2, MFMA both GEMMs, in-place -------
__global__ __launch_bounds__(256) void attn1_mfma(const float* __restrict__ q,
                                                  const float* __restrict__ kl,
                                                  const float* __restrict__ w2t,
                                                  float* __restrict__ oh) {
  __shared__ short Pa[16384];               // 64x256 bf16 in A-frag order
  __shared__ float redM[4][64], redS[4][64];
  __shared__ float rowM[64], rowI[64];
  const int tid = threadIdx.x;
  const int lane = tid & 63, w = tid >> 6;
  const int qd = lane >> 4, c = lane & 15;
  const int r0 = blockIdx.x * 64;
  const int bh = blockIdx.y;
  const float* qp = q + (size_t)bh * QKV_STRIDE;
  const float* klp = kl + (size_t)bh * LM_STRIDE;
  const float* w2p = w2t + (size_t)bh * LM_STRIDE;

  f32x4 acc[4][4];
#pragma unroll
  for (int i = 0; i < 4; ++i)
#pragma unroll
    for (int j = 0; j < 4; ++j) acc[i][j] = (f32x4){0.f, 0.f, 0.f, 0.f};
  // S = q_tile[64x64] @ kl^T  (cols 64w..64w+63 per wave)
#pragma unroll
  for (int st = 0; st < 2; ++st) {
    const int k0 = st * 32 + qd * 8;
    bf8 af[4], bf[4];
#pragma unroll
    for (int i = 0; i < 4; ++i) {
      float4 x0 = *(const float4*)&qp[(size_t)(r0 + i * 16 + c) * 64 + k0];
      float4 x1 = *(const float4*)&qp[(size_t)(r0 + i * 16 + c) * 64 + k0 + 4];
      af[i] = pack8(x0, x1);
      float4 y0 = *(const float4*)&klp[(size_t)(w * 64 + i * 16 + c) * 64 + k0];
      float4 y1 = *(const float4*)&klp[(size_t)(w * 64 + i * 16 + c) * 64 + k0 + 4];
      bf[i] = pack8(y0, y1);
    }
#pragma unroll
    for (int i = 0; i < 4; ++i)
#pragma unroll
      for (int j = 0; j < 4; ++j)
        acc[i][j] = __builtin_amdgcn_mfma_f32_16x16x32_bf16(af[i], bf[j], acc[i][j], 0, 0, 0);
  }
  // row max (rows: i*16 + qd*4 + r; cols split over lanes c and waves)
#pragma unroll
  for (int i = 0; i < 4; ++i)
#pragma unroll
    for (int r = 0; r < 4; ++r) {
      float m0 = fmaxf(fmaxf(acc[i][0][r], acc[i][1][r]),
                       fmaxf(acc[i][2][r], acc[i][3][r]));
      m0 = fmaxf(m0, __shfl_xor(m0, 1));
      m0 = fmaxf(m0, __shfl_xor(m0, 2));
      m0 = fmaxf(m0, __shfl_xor(m0, 4));
      m0 = fmaxf(m0, __shfl_xor(m0, 8));
      if (c == 0) redM[w][i * 16 + qd * 4 + r] = m0;
    }
  __syncthreads();
  if (tid < 64)
    rowM[tid] = fmaxf(fmaxf(redM[0][tid], redM[1][tid]),
                      fmaxf(redM[2][tid], redM[3][tid]));
  __syncthreads();
#pragma unroll
  for (int i = 0; i < 4; ++i)
#pragma unroll
    for (int r = 0; r < 4; ++r) {
      const float mrow = rowM[i * 16 + qd * 4 + r];
      float s = 0.f;
#pragma unroll
      for (int j = 0; j < 4; ++j) {
        const float e = __expf(acc[i][j][r] - mrow);
        acc[i][j][r] = e;
        s += e;
      }
      s += __shfl_xor(s, 1);
      s += __shfl_xor(s, 2);
      s += __shfl_xor(s, 4);
      s += __shfl_xor(s, 8);
      if (c == 0) redS[w][i * 16 + qd * 4 + r] = s;
    }
  __syncthreads();
  if (tid < 64)
    rowI[tid] = 1.0f / (redS[0][tid] + redS[1][tid] + redS[2][tid] + redS[3][tid]);
  __syncthreads();
  // write P (bf16) into A-frag-order LDS
#pragma unroll
  for (int i = 0; i < 4; ++i)
#pragma unroll
    for (int r = 0; r < 4; ++r) {
      const int row = i * 16 + qd * 4 + r;
      const float inv = rowI[row];
#pragma unroll
      for (int j = 0; j < 4; ++j) {
        const int col = w * 64 + j * 16 + c;
        const short val = (short)f2bf_(acc[i][j][r] * inv);
        const int kb = col >> 5;
        const int lane2 = (row & 15) + 16 * ((col >> 3) & 3);
        Pa[((kb * 4 + i) * 64 + lane2) * 8 + (col & 7)] = val;
      }
    }
  __syncthreads();
  // O = P @ w2 : wave w computes rows [16w,16w+16)
  f32x4 accO[4];
#pragma unroll
  for (int nb = 0; nb < 4; ++nb) accO[nb] = (f32x4){0.f, 0.f, 0.f, 0.f};
  for (int kb = 0; kb < 8; ++kb) {
    bf8 ap = *(const bf8*)&Pa[((kb * 4 + w) * 64 + lane) * 8];
#pragma unroll
    for (int nb = 0; nb < 4; ++nb) {
      float4 y0 = *(const float4*)&w2p[(size_t)(nb * 16 + c) * 256 + kb * 32 + qd * 8];
      float4 y1 = *(const float4*)&w2p[(size_t)(nb * 16 + c) * 256 + kb * 32 + qd * 8 + 4];
      bf8 bfr = pack8(y0, y1);
      accO[nb] = __builtin_amdgcn_mfma_f32_16x16x32_bf16(ap, bfr, accO[nb], 0, 0, 0);
    }
  }
  float* ohp = oh + (size_t)bh * QKV_STRIDE;
#pragma unroll
  for (int nb = 0; nb < 4; ++nb)
#pragma unroll
    for (int r = 0; r < 4; ++r) {
      const int row = r0 + w * 16 + qd * 4 + r;
      ohp[(size_t)row * 64 + nb * 16 + c] = accO[nb][r];
    }
}

// ---------------- depthwise conv residual: oh += conv(v) --------------------
__global__ __launch_bounds__(256) void conv_res(const float* __restrict__ v,
                                                const float* __restrict__ cw,
                                                float* __restrict__ oh) {
  const int g = blockIdx.x * 256 + threadIdx.x;
  const int dd = g & 63, i = (g >> 6) & 4095, bh = g >> 18;
  const int h = bh & 7;
  float acc = oh[g];
  const size_t base = (size_t)bh * QKV_STRIDE + dd;
#pragma unroll
  for (int t = 0; t < 33; ++t) {
    const int si = i + t - 16;
    if (si >= 0 && si < 4096) acc += cw[h * 33 + t] * v[base + (size_t)si * 64];
  }
  oh[g] = acc;
}

// ---------------- out = concat_heads(oh) @ w_out + b_out (MFMA) -------------
__global__ __launch_bounds__(256) void gemm_out_mfma(const float* __restrict__ oh,
                                                     const short* __restrict__ wT,
                                                     const float* __restrict__ bias,
                                                     float* __restrict__ out) {
  __shared__ short As[4096];
  __shared__ short Bs[4096];
  const int tid = threadIdx.x;
  const int lane = tid & 63, w = tid >> 6;
  const int wr = w >> 1, wc = w & 1;
  const int gm0 = blockIdx.x * 128, gn0 = blockIdx.y * 128;
  const int mA0 = (tid >> 6) * 16 + (tid & 15), kA0 = ((tid >> 4) & 3) * 8;
  const int s1 = tid + 256;
  const int mA1 = (s1 >> 6) * 16 + (s1 & 15), kA1 = ((s1 >> 4) & 3) * 8;
  const int b0r = (gm0 + mA0) >> 12, seq0 = (gm0 + mA0) & 4095;
  const int b1r = (gm0 + mA1) >> 12, seq1 = (gm0 + mA1) & 4095;
  f32x4 acc[4][4];
#pragma unroll
  for (int i = 0; i < 4; ++i)
#pragma unroll
    for (int j = 0; j < 4; ++j) acc[i][j] = (f32x4){0.f, 0.f, 0.f, 0.f};
  for (int kt = 0; kt < 16; ++kt) {
    const int k0 = kt * 32;
    const int ka = k0 + kA0, kb = k0 + kA1;
    float4 a0 = *(const float4*)&oh[(size_t)(b0r * 8 + (ka >> 6)) * QKV_STRIDE + seq0 * 64 + (ka & 63)];
    float4 a1 = *(const float4*)&oh[(size_t)(b0r * 8 + (ka >> 6)) * QKV_STRIDE + seq0 * 64 + (ka & 63) + 4];
    float4 a2 = *(const float4*)&oh[(size_t)(b1r * 8 + (kb >> 6)) * QKV_STRIDE + seq1 * 64 + (kb & 63)];
    float4 a3 = *(const float4*)&oh[(size_t)(b1r * 8 + (kb >> 6)) * QKV_STRIDE + seq1 * 64 + (kb & 63) + 4];
    bf8 bb0 = *(const bf8*)&wT[(size_t)(gn0 + mA0) * 512 + ka];
    bf8 bb1 = *(const bf8*)&wT[(size_t)(gn0 + mA1) * 512 + kb];
    __syncthreads();
    *(bf8*)&As[tid * 8] = pack8(a0, a1);
    *(bf8*)&As[s1 * 8] = pack8(a2, a3);
    *(bf8*)&Bs[tid * 8] = bb0;
    *(bf8*)&Bs[s1 * 8] = bb1;
    __syncthreads();
    bf8 af[4], bfr[4];
#pragma unroll
    for (int i = 0; i < 4; ++i) {
      af[i] = *(const bf8*)&As[((wr * 4 + i) * 64 + lane) * 8];
      bfr[i] = *(const bf8*)&Bs[((wc * 4 + i) * 64 + lane) * 8];
    }
#pragma unroll
    for (int i = 0; i < 4; ++i)
#pragma unroll
      for (int j = 0; j < 4; ++j)
        acc[i][j] = __builtin_amdgcn_mfma_f32_16x16x32_bf16(af[i], bfr[j], acc[i][j], 0, 0, 0);
  }
  const int qd = lane >> 4, c = lane & 15;
#pragma unroll
  for (int i = 0; i < 4; ++i)
#pragma unroll
    for (int j = 0; j < 4; ++j) {
      const int col = gn0 + wc * 64 + j * 16 + c;
      const float bval = bias[col];
#pragma unroll
      for (int r = 0; r < 4; ++r) {
        const int row = gm0 + wr * 64 + i * 16 + qd * 4 + r;
        out[(size_t)row * 512 + col] = acc[i][j][r] + bval;
      }
    }
}

// ---------------------------------------------------------------------------
extern "C" void kernel_launch(void* const* d_in, const int* in_sizes, int n_in,
                              void* d_out, int out_size, void* d_ws, size_t ws_size,
                              hipStream_t stream) {
  const float* x    = (const float*)d_in[0];
  const float* wqkv = (const float*)d_in[1];
  const float* wout = (const float*)d_in[2];
  const float* bout = (const float*)d_in[3];
  const float* cw   = (const float*)d_in[4];
  float* out = (float*)d_out;

  float* w = (float*)d_ws;
  float* q    = w;                       // [4,8,4096,64] fp32 (reused as oh)
  float* k    = w + 8388608;
  float* v    = w + 16777216;
  float* ql   = w + 25165824;
  float* kl   = ql + 524288;
  float* x2   = kl + 524288;             // [32,256,256]
  float* z0   = x2 + 2097152;
  float* z0t  = z0 + 2097152;
  float* z1   = z0t + 2097152;
  float* z1t  = z1 + 2097152;
  float* xz   = z1t + 2097152;
  float* xzt  = xz + 2097152;
  float* u1t  = xzt + 2097152;
  float* u2t  = u1t + 2097152;
  float* av   = u2t + 2097152;           // [32,256,64]
  float* w2t  = av + 524288;             // [32,64,256]
  float* marr = w2t + 524288;
  float* larr = marr + 8192;
  float* scal = larr + 8192;             // [2]
  short* wqkvT = (short*)(w + 46153732); // [1536,512] bf16
  short* woutT = (short*)(w + 46546948); // [512,512] bf16

  zero_scal<<<1, 64, 0, stream>>>(scal);
  transpose_bf16<<<dim3(48, 16), 256, 0, stream>>>(wqkv, wqkvT, 512, 1536);
  transpose_bf16<<<dim3(16, 16), 256, 0, stream>>>(wout, woutT, 512, 512);
  gemm_qkv_mfma<<<dim3(128, 12), 256, 0, stream>>>(x, wqkvT, q, k, v);
  lmk_mean<<<2048, 256, 0, stream>>>(q, k, ql, kl);
  sim2_softmax<<<512, 256, 0, stream>>>(ql, kl, x2);
  colrow_max<<<32, 256, 0, stream>>>(x2, scal);
  tscale2<<<8192, 256, 0, stream>>>(x2, scal, z0, z0t);

  float *zc = z0, *zct = z0t, *zn = z1, *znt = z1t;
  for (int it = 0; it < 6; ++it) {
    // xz = x2 @ zc            (write xz and xz^T)
    pinv_mfma<<<dim3(16, 32), 256, 0, stream>>>(x2, zct, x2, xz, xzt, 0.f, 1.f, 1, 1);
    // u1 = 7*xz - xz@xz       (write u1^T only)
    pinv_mfma<<<dim3(16, 32), 256, 0, stream>>>(xz, xzt, xz, u1t, u1t, 7.f, -1.f, 0, 1);
    // u2 = 15*xz - xz@u1      (write u2^T only)
    pinv_mfma<<<dim3(16, 32), 256, 0, stream>>>(xz, u1t, xz, u2t, u2t, 15.f, -1.f, 0, 1);
    // zn = 3.25*zc - 0.25*zc@u2  (write zn and zn^T)
    pinv_mfma<<<dim3(16, 32), 256, 0, stream>>>(zc, u2t, zc, zn, znt, 3.25f, -0.25f, 1, 1);
    float* t;
    t = zc; zc = zn; zn = t;
    t = zct; zct = znt; znt = t;
  }

  attn3_ml<<<512, 256, 0, stream>>>(ql, k, marr, larr);
  attn3_av<<<512, 256, 0, stream>>>(ql, k, v, marr, larr, av);
  zav_gemm_t<<<dim3(32, 4), 256, 0, stream>>>(zc, av, w2t);
  attn1_mfma<<<dim3(64, 32), 256, 0, stream>>>(q, kl, w2t, q /* in-place */);
  conv_res<<<32768, 256, 0, stream>>>(v, cw, q);
  gemm_out_mfma<<<dim3(128, 4), 256, 0, stream>>>(q, woutT, bout, out);
}

// Round 3
// 1214.185 us; speedup vs baseline: 1.9045x; 1.4011x over previous
//
#include <hip/hip_runtime.h>
#include <math.h>

// ---------------------------------------------------------------------------
// NystromAttention round 3: + MFMA flash for attn3 (was 790us fp32 2-pass).
// b=4 n=4096 dim=512 h=8 d=64 m=256, l=16, iters=6, conv k=33.
// MFMA 16x16x32_bf16 layouts (HW-verified per guide):
//   A: m=lane&15, k=(lane>>4)*8+j    B: n=lane&15, k=(lane>>4)*8+j
//   C/D: col=lane&15, row=(lane>>4)*4+reg
// ---------------------------------------------------------------------------

#define QKV_STRIDE 262144   // 4096*64 per (b,h)
#define LM_STRIDE 16384     // 256*64
#define MM_STRIDE 65536     // 256*256

typedef float f32x4 __attribute__((ext_vector_type(4)));
typedef short bf8 __attribute__((ext_vector_type(8)));   // 8 bf16 in 4 VGPRs
typedef short s4v __attribute__((ext_vector_type(4)));

__device__ __forceinline__ unsigned short f2bf_(float f) {
  unsigned u = __float_as_uint(f);
  u += 0x7FFFu + ((u >> 16) & 1u);   // RNE
  return (unsigned short)(u >> 16);
}
__device__ __forceinline__ float bf2f_(unsigned short h) {
  return __uint_as_float(((unsigned)h) << 16);
}
__device__ __forceinline__ bf8 pack8(const float4 a, const float4 b) {
  bf8 r;
  r[0] = (short)f2bf_(a.x); r[1] = (short)f2bf_(a.y);
  r[2] = (short)f2bf_(a.z); r[3] = (short)f2bf_(a.w);
  r[4] = (short)f2bf_(b.x); r[5] = (short)f2bf_(b.y);
  r[6] = (short)f2bf_(b.z); r[7] = (short)f2bf_(b.w);
  return r;
}

__global__ __launch_bounds__(256) void zero_scal(float* scal) {
  if (threadIdx.x < 2) scal[threadIdx.x] = 0.0f;
}

// ------------- transpose + fp32->bf16: dst[C][R] = bf16(src[R][C]) ----------
__global__ __launch_bounds__(256) void transpose_bf16(const float* __restrict__ src,
                                                      short* __restrict__ dst,
                                                      int R, int C) {
  __shared__ float T[32][33];
  const int t = threadIdx.x;
  const int c0 = blockIdx.x * 32, r0 = blockIdx.y * 32;
  const int tr = t >> 3, tc = (t & 7) << 2;
  float4 vsrc = *(const float4*)&src[(size_t)(r0 + tr) * C + c0 + tc];
  T[tr][tc + 0] = vsrc.x; T[tr][tc + 1] = vsrc.y;
  T[tr][tc + 2] = vsrc.z; T[tr][tc + 3] = vsrc.w;
  __syncthreads();
  s4v o;
  o[0] = (short)f2bf_(T[tc + 0][tr]);
  o[1] = (short)f2bf_(T[tc + 1][tr]);
  o[2] = (short)f2bf_(T[tc + 2][tr]);
  o[3] = (short)f2bf_(T[tc + 3][tr]);
  *(s4v*)&dst[(size_t)(c0 + tr) * R + r0 + tc] = o;
}

// ------------- qkv = x @ w_qkv via MFMA; scatter to q/k/v, q*=0.125 ---------
__global__ __launch_bounds__(256) void gemm_qkv_mfma(const float* __restrict__ x,
                                                     const short* __restrict__ wT,
                                                     float* __restrict__ q,
                                                     float* __restrict__ k,
                                                     float* __restrict__ v) {
  __shared__ short As[4096];  // 128x32 frag-order
  __shared__ short Bs[4096];
  const int tid = threadIdx.x;
  const int lane = tid & 63, w = tid >> 6;
  const int wr = w >> 1, wc = w & 1;
  const int gm0 = blockIdx.x * 128, gn0 = blockIdx.y * 128;
  const int mA0 = (tid >> 6) * 16 + (tid & 15), kA0 = ((tid >> 4) & 3) * 8;
  const int s1 = tid + 256;
  const int mA1 = (s1 >> 6) * 16 + (s1 & 15), kA1 = ((s1 >> 4) & 3) * 8;
  f32x4 acc[4][4];
#pragma unroll
  for (int i = 0; i < 4; ++i)
#pragma unroll
    for (int j = 0; j < 4; ++j) acc[i][j] = (f32x4){0.f, 0.f, 0.f, 0.f};
  for (int kt = 0; kt < 16; ++kt) {
    const int k0 = kt * 32;
    float4 a0 = *(const float4*)&x[(size_t)(gm0 + mA0) * 512 + k0 + kA0];
    float4 a1 = *(const float4*)&x[(size_t)(gm0 + mA0) * 512 + k0 + kA0 + 4];
    float4 a2 = *(const float4*)&x[(size_t)(gm0 + mA1) * 512 + k0 + kA1];
    float4 a3 = *(const float4*)&x[(size_t)(gm0 + mA1) * 512 + k0 + kA1 + 4];
    bf8 b0 = *(const bf8*)&wT[(size_t)(gn0 + mA0) * 512 + k0 + kA0];
    bf8 b1 = *(const bf8*)&wT[(size_t)(gn0 + mA1) * 512 + k0 + kA1];
    __syncthreads();
    *(bf8*)&As[tid * 8] = pack8(a0, a1);
    *(bf8*)&As[s1 * 8] = pack8(a2, a3);
    *(bf8*)&Bs[tid * 8] = b0;
    *(bf8*)&Bs[s1 * 8] = b1;
    __syncthreads();
    bf8 af[4], bf[4];
#pragma unroll
    for (int i = 0; i < 4; ++i) {
      af[i] = *(const bf8*)&As[((wr * 4 + i) * 64 + lane) * 8];
      bf[i] = *(const bf8*)&Bs[((wc * 4 + i) * 64 + lane) * 8];
    }
#pragma unroll
    for (int i = 0; i < 4; ++i)
#pragma unroll
      for (int j = 0; j < 4; ++j)
        acc[i][j] = __builtin_amdgcn_mfma_f32_16x16x32_bf16(af[i], bf[j], acc[i][j], 0, 0, 0);
  }
  const int which = blockIdx.y >> 2;  // 0:q 1:k 2:v
  float* dst = which == 0 ? q : (which == 1 ? k : v);
  const float scale = which == 0 ? 0.125f : 1.0f;
  const int qd = lane >> 4, c = lane & 15;
#pragma unroll
  for (int i = 0; i < 4; ++i) {
#pragma unroll
    for (int j = 0; j < 4; ++j) {
      const int col = gn0 + wc * 64 + j * 16 + c;
      const int head = (col >> 6) & 7, dd = col & 63;
#pragma unroll
      for (int r = 0; r < 4; ++r) {
        const int row = gm0 + wr * 64 + i * 16 + qd * 4 + r;
        const int b = row >> 12, seq = row & 4095;
        dst[(size_t)(b * 8 + head) * QKV_STRIDE + seq * 64 + dd] = acc[i][j][r] * scale;
      }
    }
  }
}

// ---------------- landmark means ------------------------------------------
__global__ __launch_bounds__(256) void lmk_mean(const float* __restrict__ q,
                                                const float* __restrict__ k,
                                                float* __restrict__ ql,
                                                float* __restrict__ kl) {
  const int g = blockIdx.x * 256 + threadIdx.x;
  const int dd = g & 63, mi = (g >> 6) & 255, bh = g >> 14;
  const size_t base = (size_t)bh * QKV_STRIDE + mi * 1024 + dd;
  float sq = 0.f, sk = 0.f;
#pragma unroll
  for (int jj = 0; jj < 16; ++jj) {
    sq += q[base + jj * 64];
    sk += k[base + jj * 64];
  }
  ql[g] = sq * 0.0625f;
  kl[g] = sk * 0.0625f;
}

// ------- prep: kb16[seq][d] = bf16(k);  vT16[d][seq] = bf16(v) --------------
__global__ __launch_bounds__(256) void prep_kv(const float* __restrict__ k,
                                               const float* __restrict__ v,
                                               short* __restrict__ kb16,
                                               short* __restrict__ vT16) {
  const int bh = blockIdx.x >> 6, s0 = (blockIdx.x & 63) * 64;
  __shared__ short Tv[64][68];
  const int tid = threadIdx.x;
  const int tr = tid >> 2, tc = (tid & 3) * 16;
  const size_t base = (size_t)bh * QKV_STRIDE + (size_t)(s0 + tr) * 64 + tc;
#pragma unroll
  for (int u = 0; u < 4; ++u) {
    float4 kk = *(const float4*)&k[base + u * 4];
    s4v ks;
    ks[0] = (short)f2bf_(kk.x); ks[1] = (short)f2bf_(kk.y);
    ks[2] = (short)f2bf_(kk.z); ks[3] = (short)f2bf_(kk.w);
    *(s4v*)&kb16[base + u * 4] = ks;
    float4 vv = *(const float4*)&v[base + u * 4];
    Tv[tr][tc + u * 4 + 0] = (short)f2bf_(vv.x);
    Tv[tr][tc + u * 4 + 1] = (short)f2bf_(vv.y);
    Tv[tr][tc + u * 4 + 2] = (short)f2bf_(vv.z);
    Tv[tr][tc + u * 4 + 3] = (short)f2bf_(vv.w);
  }
  __syncthreads();
  const int d = tid >> 2, sgrp = (tid & 3) * 16;
#pragma unroll
  for (int u = 0; u < 2; ++u) {
    bf8 o;
#pragma unroll
    for (int ii = 0; ii < 8; ++ii) o[ii] = Tv[sgrp + u * 8 + ii][d];
    *(bf8*)&vT16[(size_t)bh * QKV_STRIDE + (size_t)d * 4096 + s0 + sgrp + u * 8] = o;
  }
}

// ---------------- sim2 = ql @ kl^T, softmax -> x2 ---------------------------
__global__ __launch_bounds__(256) void sim2_softmax(const float* __restrict__ ql,
                                                    const float* __restrict__ kl,
                                                    float* __restrict__ x2) {
  const int blk = blockIdx.x;
  const int bh = blk >> 4, rg = blk & 15;
  __shared__ float Qs[16][64];
  __shared__ float Ks[64][68];
  __shared__ float S[16][257];
  __shared__ float red[16][17];
  __shared__ float rowinv[16];
  const int tid = threadIdx.x;
  const int r = tid >> 4, jc = tid & 15;
#pragma unroll
  for (int u = 0; u < 4; ++u) {
    int t2 = tid + u * 256;
    Qs[t2 >> 6][t2 & 63] =
        ql[(size_t)bh * LM_STRIDE + (rg * 16 + (t2 >> 6)) * 64 + (t2 & 63)];
  }
  for (int c = 0; c < 4; ++c) {
    __syncthreads();
#pragma unroll
    for (int u = 0; u < 4; ++u) {
      int t4 = tid + u * 256;
      int row = t4 >> 4, c4 = (t4 & 15) << 2;
      *(float4*)&Ks[row][c4] =
          *(const float4*)&kl[(size_t)bh * LM_STRIDE + (c * 64 + row) * 64 + c4];
    }
    __syncthreads();
#pragma unroll
    for (int s = 0; s < 4; ++s) {
      const int jj = jc + (s << 4);
      float acc = 0.f;
#pragma unroll
      for (int k4 = 0; k4 < 16; ++k4) {
        const float4 a = *(const float4*)&Qs[r][k4 << 2];
        const float4 bb = *(const float4*)&Ks[jj][k4 << 2];
        acc += a.x * bb.x + a.y * bb.y + a.z * bb.z + a.w * bb.w;
      }
      S[r][(c << 6) + jj] = acc;
    }
  }
  __syncthreads();
  float pm = -3.0e38f;
#pragma unroll
  for (int u = 0; u < 16; ++u) pm = fmaxf(pm, S[r][jc + (u << 4)]);
  red[r][jc] = pm;
  __syncthreads();
  float m = red[r][0];
#pragma unroll
  for (int u = 1; u < 16; ++u) m = fmaxf(m, red[r][u]);
  __syncthreads();
  float ps = 0.f;
#pragma unroll
  for (int u = 0; u < 16; ++u) {
    const int j = jc + (u << 4);
    const float e = __expf(S[r][j] - m);
    S[r][j] = e;
    ps += e;
  }
  red[r][jc] = ps;
  __syncthreads();
  if (jc == 0) {
    float sum = 0.f;
#pragma unroll
    for (int u = 0; u < 16; ++u) sum += red[r][u];
    rowinv[r] = 1.0f / sum;
  }
  __syncthreads();
  for (int idx = tid; idx < 4096; idx += 256) {
    const int rr = idx >> 8, j = idx & 255;
    x2[(size_t)bh * MM_STRIDE + (rg * 16 + rr) * 256 + j] = S[rr][j] * rowinv[rr];
  }
}

// ---------------- global max of col/row abs-sums ----------------------------
__global__ __launch_bounds__(256) void colrow_max(const float* __restrict__ x2,
                                                  float* __restrict__ scal) {
  const int bh = blockIdx.x;
  const int tid = threadIdx.x;
  const float* xb = x2 + (size_t)bh * MM_STRIDE;
  float cs = 0.f, rs = 0.f;
  for (int j = 0; j < 256; ++j) cs += fabsf(xb[tid * 256 + j]);
  for (int i = 0; i < 256; ++i) rs += fabsf(xb[i * 256 + tid]);
  __shared__ float rc[256], rr[256];
  rc[tid] = cs; rr[tid] = rs;
  __syncthreads();
  for (int st = 128; st > 0; st >>= 1) {
    if (tid < st) {
      rc[tid] = fmaxf(rc[tid], rc[tid + st]);
      rr[tid] = fmaxf(rr[tid], rr[tid + st]);
    }
    __syncthreads();
  }
  if (tid == 0) {
    atomicMax((int*)&scal[0], __float_as_int(rc[0]));
    atomicMax((int*)&scal[1], __float_as_int(rr[0]));
  }
}

// --------- z0 = x2^T/(cmax*rmax), z0t = x2/(cmax*rmax) ----------------------
__global__ __launch_bounds__(256) void tscale2(const float* __restrict__ x2,
                                               const float* __restrict__ scal,
                                               float* __restrict__ z0,
                                               float* __restrict__ z0t) {
  const int g = blockIdx.x * 256 + threadIdx.x;
  const int j = g & 255, i = (g >> 8) & 255, bh = g >> 16;
  const float inv = 1.0f / (scal[0] * scal[1]);
  const float val = x2[g] * inv;      // x2[bh][i][j]
  z0t[g] = val;
  z0[(size_t)bh * MM_STRIDE + j * 256 + i] = val;
}

// --------- split-bf16 batched 256^3: C = alpha*E + beta*(A@B) ---------------
__global__ __launch_bounds__(256) void pinv_mfma(const float* __restrict__ A,
                                                 const float* __restrict__ BT,
                                                 const float* __restrict__ E,
                                                 float* __restrict__ C,
                                                 float* __restrict__ CT,
                                                 float alpha, float beta,
                                                 int wantC, int wantT) {
  __shared__ short Ahi[2048], Alo[2048], Bhi[2048], Blo[2048];  // 64x32 each
  const int tid = threadIdx.x;
  const int lane = tid & 63, w = tid >> 6;
  const int batch = blockIdx.y;
  const int tm = blockIdx.x >> 2, tn = blockIdx.x & 3;
  const float* Ab = A + (size_t)batch * MM_STRIDE;
  const float* BTb = BT + (size_t)batch * MM_STRIDE;
  const float* Eb = E + (size_t)batch * MM_STRIDE;
  const int ml = (tid >> 6) * 16 + (tid & 15), koff = ((tid >> 4) & 3) * 8;
  f32x4 acc[4];
#pragma unroll
  for (int j = 0; j < 4; ++j) acc[j] = (f32x4){0.f, 0.f, 0.f, 0.f};
  for (int kt = 0; kt < 8; ++kt) {
    const int k0 = kt * 32;
    float4 a0 = *(const float4*)&Ab[(size_t)(tm * 64 + ml) * 256 + k0 + koff];
    float4 a1 = *(const float4*)&Ab[(size_t)(tm * 64 + ml) * 256 + k0 + koff + 4];
    float4 b0 = *(const float4*)&BTb[(size_t)(tn * 64 + ml) * 256 + k0 + koff];
    float4 b1 = *(const float4*)&BTb[(size_t)(tn * 64 + ml) * 256 + k0 + koff + 4];
    __syncthreads();
    {
      bf8 hi, lo;
      const float fa[8] = {a0.x, a0.y, a0.z, a0.w, a1.x, a1.y, a1.z, a1.w};
#pragma unroll
      for (int e = 0; e < 8; ++e) {
        unsigned short h = f2bf_(fa[e]);
        hi[e] = (short)h;
        lo[e] = (short)f2bf_(fa[e] - bf2f_(h));
      }
      *(bf8*)&Ahi[tid * 8] = hi;
      *(bf8*)&Alo[tid * 8] = lo;
      const float fb[8] = {b0.x, b0.y, b0.z, b0.w, b1.x, b1.y, b1.z, b1.w};
#pragma unroll
      for (int e = 0; e < 8; ++e) {
        unsigned short h = f2bf_(fb[e]);
        hi[e] = (short)h;
        lo[e] = (short)f2bf_(fb[e] - bf2f_(h));
      }
      *(bf8*)&Bhi[tid * 8] = hi;
      *(bf8*)&Blo[tid * 8] = lo;
    }
    __syncthreads();
    bf8 ah = *(const bf8*)&Ahi[(w * 64 + lane) * 8];
    bf8 al = *(const bf8*)&Alo[(w * 64 + lane) * 8];
#pragma unroll
    for (int j = 0; j < 4; ++j) {
      bf8 bh = *(const bf8*)&Bhi[(j * 64 + lane) * 8];
      bf8 bl = *(const bf8*)&Blo[(j * 64 + lane) * 8];
      acc[j] = __builtin_amdgcn_mfma_f32_16x16x32_bf16(ah, bh, acc[j], 0, 0, 0);
      acc[j] = __builtin_amdgcn_mfma_f32_16x16x32_bf16(ah, bl, acc[j], 0, 0, 0);
      acc[j] = __builtin_amdgcn_mfma_f32_16x16x32_bf16(al, bh, acc[j], 0, 0, 0);
    }
  }
  float* Cb = C + (size_t)batch * MM_STRIDE;
  float* CTb = CT + (size_t)batch * MM_STRIDE;
  const int qd = lane >> 4, c = lane & 15;
#pragma unroll
  for (int j = 0; j < 4; ++j) {
    const int col = tn * 64 + j * 16 + c;
#pragma unroll
    for (int r = 0; r < 4; ++r) {
      const int row = tm * 64 + w * 16 + qd * 4 + r;
      const float val = alpha * Eb[(size_t)row * 256 + col] + beta * acc[j][r];
      if (wantC) Cb[(size_t)row * 256 + col] = val;
      if (wantT) CTb[(size_t)col * 256 + row] = val;
    }
  }
}

// ---- attn3 flash: O_part = exp(ql@k^T - m) @ v over a 1024-key chunk -------
__global__ __launch_bounds__(256) void attn3_flash(const float* __restrict__ ql,
                                                   const short* __restrict__ kb16,
                                                   const short* __restrict__ vT16,
                                                   float* __restrict__ opart,
                                                   float* __restrict__ mpart,
                                                   float* __restrict__ lpart) {
  const int kc = blockIdx.x;   // key chunk 0..3 (1024 keys each)
  const int rt = blockIdx.y;   // row tile 0..3 (64 rows each)
  const int bh = blockIdx.z;   // 0..31
  __shared__ short Pa[16384];  // 64 rows x 256 keys, A-frag order
  __shared__ float redM[4][64], redS[4][64];
  __shared__ float mRow[64], lRow[64], alphaRow[64];
  const int tid = threadIdx.x, lane = tid & 63, w = tid >> 6;
  const int qd = lane >> 4, c = lane & 15;
  const int r0 = rt * 64;
  const float* qlp = ql + (size_t)bh * LM_STRIDE;
  const short* kp = kb16 + (size_t)bh * QKV_STRIDE;
  const short* vp = vT16 + (size_t)bh * QKV_STRIDE;
  // A-frags for the 64 ql rows
  bf8 af[2][4];
#pragma unroll
  for (int st = 0; st < 2; ++st)
#pragma unroll
    for (int i = 0; i < 4; ++i) {
      float4 x0 = *(const float4*)&qlp[(size_t)(r0 + i * 16 + c) * 64 + st * 32 + qd * 8];
      float4 x1 = *(const float4*)&qlp[(size_t)(r0 + i * 16 + c) * 64 + st * 32 + qd * 8 + 4];
      af[st][i] = pack8(x0, x1);
    }
  if (tid < 64) { mRow[tid] = -3.0e38f; lRow[tid] = 0.f; }
  f32x4 accO[4];
#pragma unroll
  for (int nb = 0; nb < 4; ++nb) accO[nb] = (f32x4){0.f, 0.f, 0.f, 0.f};
  __syncthreads();
  for (int it = 0; it < 4; ++it) {
    const int kb0 = kc * 1024 + it * 256;
    f32x4 acc[4][4];
#pragma unroll
    for (int i = 0; i < 4; ++i)
#pragma unroll
      for (int j = 0; j < 4; ++j) acc[i][j] = (f32x4){0.f, 0.f, 0.f, 0.f};
#pragma unroll
    for (int st = 0; st < 2; ++st) {
      bf8 bfk[4];
#pragma unroll
      for (int j = 0; j < 4; ++j)
        bfk[j] = *(const bf8*)&kp[(size_t)(kb0 + w * 64 + j * 16 + c) * 64 + st * 32 + qd * 8];
#pragma unroll
      for (int i = 0; i < 4; ++i)
#pragma unroll
        for (int j = 0; j < 4; ++j)
          acc[i][j] = __builtin_amdgcn_mfma_f32_16x16x32_bf16(af[st][i], bfk[j], acc[i][j], 0, 0, 0);
    }
    // wave-local row max
#pragma unroll
    for (int i = 0; i < 4; ++i)
#pragma unroll
      for (int r = 0; r < 4; ++r) {
        float m0 = fmaxf(fmaxf(acc[i][0][r], acc[i][1][r]),
                         fmaxf(acc[i][2][r], acc[i][3][r]));
        m0 = fmaxf(m0, __shfl_xor(m0, 1));
        m0 = fmaxf(m0, __shfl_xor(m0, 2));
        m0 = fmaxf(m0, __shfl_xor(m0, 4));
        m0 = fmaxf(m0, __shfl_xor(m0, 8));
        if (c == 0) redM[w][i * 16 + qd * 4 + r] = m0;
      }
    __syncthreads();                                   // A
    if (tid < 64) {
      float mN = fmaxf(fmaxf(redM[0][tid], redM[1][tid]),
                       fmaxf(redM[2][tid], redM[3][tid]));
      mN = fmaxf(mN, mRow[tid]);
      const float a = __expf(mRow[tid] - mN);
      alphaRow[tid] = a;
      mRow[tid] = mN;
      lRow[tid] *= a;
    }
    __syncthreads();                                   // B
#pragma unroll
    for (int r = 0; r < 4; ++r) {
      const float a = alphaRow[w * 16 + qd * 4 + r];
#pragma unroll
      for (int nb = 0; nb < 4; ++nb) accO[nb][r] *= a;
    }
#pragma unroll
    for (int i = 0; i < 4; ++i)
#pragma unroll
      for (int r = 0; r < 4; ++r) {
        const int row = i * 16 + qd * 4 + r;
        const float mrow = mRow[row];
        float s = 0.f;
#pragma unroll
        for (int j = 0; j < 4; ++j) {
          const float e = __expf(acc[i][j][r] - mrow);
          acc[i][j][r] = e;
          s += e;
        }
        s += __shfl_xor(s, 1);
        s += __shfl_xor(s, 2);
        s += __shfl_xor(s, 4);
        s += __shfl_xor(s, 8);
        if (c == 0) redS[w][row] = s;
      }
    __syncthreads();                                   // C
    if (tid < 64)
      lRow[tid] += redS[0][tid] + redS[1][tid] + redS[2][tid] + redS[3][tid];
    // P -> LDS, A-frag order (key is k-dim)
#pragma unroll
    for (int i = 0; i < 4; ++i)
#pragma unroll
      for (int r = 0; r < 4; ++r) {
        const int row = i * 16 + qd * 4 + r;
#pragma unroll
        for (int j = 0; j < 4; ++j) {
          const int col = w * 64 + j * 16 + c;
          const int kbk = col >> 5;
          const int lane2 = (row & 15) + 16 * ((col >> 3) & 3);
          Pa[((kbk * 4 + i) * 64 + lane2) * 8 + (col & 7)] = (short)f2bf_(acc[i][j][r]);
        }
      }
    __syncthreads();                                   // D
    // O += P @ V (wave w: rows 16w..16w+15)
#pragma unroll
    for (int kbk = 0; kbk < 8; ++kbk) {
      bf8 ap = *(const bf8*)&Pa[((kbk * 4 + w) * 64 + lane) * 8];
#pragma unroll
      for (int nb = 0; nb < 4; ++nb) {
        bf8 bv = *(const bf8*)&vp[(size_t)(nb * 16 + c) * 4096 + kb0 + kbk * 32 + qd * 8];
        accO[nb] = __builtin_amdgcn_mfma_f32_16x16x32_bf16(ap, bv, accO[nb], 0, 0, 0);
      }
    }
    __syncthreads();                                   // E
  }
  const size_t ob = ((size_t)kc * 32 + bh) * 256 + r0;
#pragma unroll
  for (int nb = 0; nb < 4; ++nb)
#pragma unroll
    for (int r = 0; r < 4; ++r)
      opart[(ob + w * 16 + qd * 4 + r) * 64 + nb * 16 + c] = accO[nb][r];
  if (tid < 64) {
    mpart[ob + tid] = mRow[tid];
    lpart[ob + tid] = lRow[tid];
  }
}

// ---------------- merge the 4 key-chunk partials -> av ----------------------
__global__ __launch_bounds__(256) void attn3_merge(const float* __restrict__ opart,
                                                   const float* __restrict__ mpart,
                                                   const float* __restrict__ lpart,
                                                   float* __restrict__ av) {
  const int g = blockIdx.x * 256 + threadIdx.x;   // 524288 = 32*256*64
  const int d = g & 63;
  const int idx = g >> 6;                          // bh*256+row
  const float m0 = mpart[idx], m1 = mpart[8192 + idx],
              m2 = mpart[16384 + idx], m3 = mpart[24576 + idx];
  const float mx = fmaxf(fmaxf(m0, m1), fmaxf(m2, m3));
  const float w0 = __expf(m0 - mx), w1 = __expf(m1 - mx),
              w2 = __expf(m2 - mx), w3 = __expf(m3 - mx);
  const float l = lpart[idx] * w0 + lpart[8192 + idx] * w1 +
                  lpart[16384 + idx] * w2 + lpart[24576 + idx] * w3;
  const float o = opart[(size_t)idx * 64 + d] * w0 +
                  opart[524288 + (size_t)idx * 64 + d] * w1 +
                  opart[1048576 + (size_t)idx * 64 + d] * w2 +
                  opart[1572864 + (size_t)idx * 64 + d] * w3;
  av[g] = o / l;
}

// ---------------- w2^T = (z_final @ av)^T : stores w2t[d][i] ----------------
__global__ __launch_bounds__(256) void zav_gemm_t(const float* __restrict__ z,
                                                  const float* __restrict__ av,
                                                  float* __restrict__ w2t) {
  const int bh = blockIdx.x;
  const int rq = blockIdx.y;
  __shared__ float Av[256][64];
  const int tid = threadIdx.x;
#pragma unroll
  for (int u = 0; u < 16; ++u) {
    int t4 = tid + u * 256;
    int row = t4 >> 4, c4 = (t4 & 15) << 2;
    *(float4*)&Av[row][c4] = *(const float4*)&av[(size_t)bh * LM_STRIDE + row * 64 + c4];
  }
  __syncthreads();
  const int d = tid & 63, rg4 = tid >> 6;
  for (int s = 0; s < 16; ++s) {
    const int i = rq * 64 + s * 4 + rg4;
    const float* zr = z + (size_t)bh * MM_STRIDE + i * 256;
    float acc = 0.f;
#pragma unroll 8
    for (int j = 0; j < 256; ++j) acc += zr[j] * Av[j][d];
    w2t[(size_t)bh * LM_STRIDE + d * 256 + i] = acc;
  }
}

// -------- attn1: oh = softmax(q@kl^T) @ w2, MFMA both GEMMs, in-place -------
__global__ __launch_bounds__(256) void attn1_mfma(const float* __restrict__ q,
                                                  const float* __restrict__ kl,
                                                  const float* __restrict__ w2t,
                                                  float* __restrict__ oh) {
  __shared__ short Pa[16384];               // 64x256 bf16 in A-frag order
  __shared__ float redM[4][64], redS[4][64];
  __shared__ float rowM[64], rowI[64];
  const int tid = threadIdx.x;
  const int lane = tid & 63, w = tid >> 6;
  const int qd = lane >> 4, c = lane & 15;
  const int r0 = blockIdx.x * 64;
  const int bh = blockIdx.y;
  const float* qp = q + (size_t)bh * QKV_STRIDE;
  const float* klp = kl + (size_t)bh * LM_STRIDE;
  const float* w2p = w2t + (size_t)bh * LM_STRIDE;

  f32x4 acc[4][4];
#pragma unroll
  for (int i = 0; i < 4; ++i)
#pragma unroll
    for (int j = 0; j < 4; ++j) acc[i][j] = (f32x4){0.f, 0.f, 0.f, 0.f};
#pragma unroll
  for (int st = 0; st < 2; ++st) {
    const int k0 = st * 32 + qd * 8;
    bf8 af[4], bf[4];
#pragma unroll
    for (int i = 0; i < 4; ++i) {
      float4 x0 = *(const float4*)&qp[(size_t)(r0 + i * 16 + c) * 64 + k0];
      float4 x1 = *(const float4*)&qp[(size_t)(r0 + i * 16 + c) * 64 + k0 + 4];
      af[i] = pack8(x0, x1);
      float4 y0 = *(const float4*)&klp[(size_t)(w * 64 + i * 16 + c) * 64 + k0];
      float4 y1 = *(const float4*)&klp[(size_t)(w * 64 + i * 16 + c) * 64 + k0 + 4];
      bf[i] = pack8(y0, y1);
    }
#pragma unroll
    for (int i = 0; i < 4; ++i)
#pragma unroll
      for (int j = 0; j < 4; ++j)
        acc[i][j] = __builtin_amdgcn_mfma_f32_16x16x32_bf16(af[i], bf[j], acc[i][j], 0, 0, 0);
  }
#pragma unroll
  for (int i = 0; i < 4; ++i)
#pragma unroll
    for (int r = 0; r < 4; ++r) {
      float m0 = fmaxf(fmaxf(acc[i][0][r], acc[i][1][r]),
                       fmaxf(acc[i][2][r], acc[i][3][r]));
      m0 = fmaxf(m0, __shfl_xor(m0, 1));
      m0 = fmaxf(m0, __shfl_xor(m0, 2));
      m0 = fmaxf(m0, __shfl_xor(m0, 4));
      m0 = fmaxf(m0, __shfl_xor(m0, 8));
      if (c == 0) redM[w][i * 16 + qd * 4 + r] = m0;
    }
  __syncthreads();
  if (tid < 64)
    rowM[tid] = fmaxf(fmaxf(redM[0][tid], redM[1][tid]),
                      fmaxf(redM[2][tid], redM[3][tid]));
  __syncthreads();
#pragma unroll
  for (int i = 0; i < 4; ++i)
#pragma unroll
    for (int r = 0; r < 4; ++r) {
      const float mrow = rowM[i * 16 + qd * 4 + r];
      float s = 0.f;
#pragma unroll
      for (int j = 0; j < 4; ++j) {
        const float e = __expf(acc[i][j][r] - mrow);
        acc[i][j][r] = e;
        s += e;
      }
      s += __shfl_xor(s, 1);
      s += __shfl_xor(s, 2);
      s += __shfl_xor(s, 4);
      s += __shfl_xor(s, 8);
      if (c == 0) redS[w][i * 16 + qd * 4 + r] = s;
    }
  __syncthreads();
  if (tid < 64)
    rowI[tid] = 1.0f / (redS[0][tid] + redS[1][tid] + redS[2][tid] + redS[3][tid]);
  __syncthreads();
#pragma unroll
  for (int i = 0; i < 4; ++i)
#pragma unroll
    for (int r = 0; r < 4; ++r) {
      const int row = i * 16 + qd * 4 + r;
      const float inv = rowI[row];
#pragma unroll
      for (int j = 0; j < 4; ++j) {
        const int col = w * 64 + j * 16 + c;
        const short val = (short)f2bf_(acc[i][j][r] * inv);
        const int kb = col >> 5;
        const int lane2 = (row & 15) + 16 * ((col >> 3) & 3);
        Pa[((kb * 4 + i) * 64 + lane2) * 8 + (col & 7)] = val;
      }
    }
  __syncthreads();
  f32x4 accO[4];
#pragma unroll
  for (int nb = 0; nb < 4; ++nb) accO[nb] = (f32x4){0.f, 0.f, 0.f, 0.f};
  for (int kb = 0; kb < 8; ++kb) {
    bf8 ap = *(const bf8*)&Pa[((kb * 4 + w) * 64 + lane) * 8];
#pragma unroll
    for (int nb = 0; nb < 4; ++nb) {
      float4 y0 = *(const float4*)&w2p[(size_t)(nb * 16 + c) * 256 + kb * 32 + qd * 8];
      float4 y1 = *(const float4*)&w2p[(size_t)(nb * 16 + c) * 256 + kb * 32 + qd * 8 + 4];
      bf8 bfr = pack8(y0, y1);
      accO[nb] = __builtin_amdgcn_mfma_f32_16x16x32_bf16(ap, bfr, accO[nb], 0, 0, 0);
    }
  }
  float* ohp = oh + (size_t)bh * QKV_STRIDE;
#pragma unroll
  for (int nb = 0; nb < 4; ++nb)
#pragma unroll
    for (int r = 0; r < 4; ++r) {
      const int row = r0 + w * 16 + qd * 4 + r;
      ohp[(size_t)row * 64 + nb * 16 + c] = accO[nb][r];
    }
}

// ---------------- depthwise conv residual: oh += conv(v) --------------------
__global__ __launch_bounds__(256) void conv_res(const float* __restrict__ v,
                                                const float* __restrict__ cw,
                                                float* __restrict__ oh) {
  const int g = blockIdx.x * 256 + threadIdx.x;
  const int dd = g & 63, i = (g >> 6) & 4095, bh = g >> 18;
  const int h = bh & 7;
  float acc = oh[g];
  const size_t base = (size_t)bh * QKV_STRIDE + dd;
#pragma unroll
  for (int t = 0; t < 33; ++t) {
    const int si = i + t - 16;
    if (si >= 0 && si < 4096) acc += cw[h * 33 + t] * v[base + (size_t)si * 64];
  }
  oh[g] = acc;
}

// ---------------- out = concat_heads(oh) @ w_out + b_out (MFMA) -------------
__global__ __launch_bounds__(256) void gemm_out_mfma(const float* __restrict__ oh,
                                                     const short* __restrict__ wT,
                                                     const float* __restrict__ bias,
                                                     float* __restrict__ out) {
  __shared__ short As[4096];
  __shared__ short Bs[4096];
  const int tid = threadIdx.x;
  const int lane = tid & 63, w = tid >> 6;
  const int wr = w >> 1, wc = w & 1;
  const int gm0 = blockIdx.x * 128, gn0 = blockIdx.y * 128;
  const int mA0 = (tid >> 6) * 16 + (tid & 15), kA0 = ((tid >> 4) & 3) * 8;
  const int s1 = tid + 256;
  const int mA1 = (s1 >> 6) * 16 + (s1 & 15), kA1 = ((s1 >> 4) & 3) * 8;
  const int b0r = (gm0 + mA0) >> 12, seq0 = (gm0 + mA0) & 4095;
  const int b1r = (gm0 + mA1) >> 12, seq1 = (gm0 + mA1) & 4095;
  f32x4 acc[4][4];
#pragma unroll
  for (int i = 0; i < 4; ++i)
#pragma unroll
    for (int j = 0; j < 4; ++j) acc[i][j] = (f32x4){0.f, 0.f, 0.f, 0.f};
  for (int kt = 0; kt < 16; ++kt) {
    const int k0 = kt * 32;
    const int ka = k0 + kA0, kb = k0 + kA1;
    float4 a0 = *(const float4*)&oh[(size_t)(b0r * 8 + (ka >> 6)) * QKV_STRIDE + seq0 * 64 + (ka & 63)];
    float4 a1 = *(const float4*)&oh[(size_t)(b0r * 8 + (ka >> 6)) * QKV_STRIDE + seq0 * 64 + (ka & 63) + 4];
    float4 a2 = *(const float4*)&oh[(size_t)(b1r * 8 + (kb >> 6)) * QKV_STRIDE + seq1 * 64 + (kb & 63)];
    float4 a3 = *(const float4*)&oh[(size_t)(b1r * 8 + (kb >> 6)) * QKV_STRIDE + seq1 * 64 + (kb & 63) + 4];
    bf8 bb0 = *(const bf8*)&wT[(size_t)(gn0 + mA0) * 512 + ka];
    bf8 bb1 = *(const bf8*)&wT[(size_t)(gn0 + mA1) * 512 + kb];
    __syncthreads();
    *(bf8*)&As[tid * 8] = pack8(a0, a1);
    *(bf8*)&As[s1 * 8] = pack8(a2, a3);
    *(bf8*)&Bs[tid * 8] = bb0;
    *(bf8*)&Bs[s1 * 8] = bb1;
    __syncthreads();
    bf8 af[4], bfr[4];
#pragma unroll
    for (int i = 0; i < 4; ++i) {
      af[i] = *(const bf8*)&As[((wr * 4 + i) * 64 + lane) * 8];
      bfr[i] = *(const bf8*)&Bs[((wc * 4 + i) * 64 + lane) * 8];
    }
#pragma unroll
    for (int i = 0; i < 4; ++i)
#pragma unroll
      for (int j = 0; j < 4; ++j)
        acc[i][j] = __builtin_amdgcn_mfma_f32_16x16x32_bf16(af[i], bfr[j], acc[i][j], 0, 0, 0);
  }
  const int qd = lane >> 4, c = lane & 15;
#pragma unroll
  for (int i = 0; i < 4; ++i)
#pragma unroll
    for (int j = 0; j < 4; ++j) {
      const int col = gn0 + wc * 64 + j * 16 + c;
      const float bval = bias[col];
#pragma unroll
      for (int r = 0; r < 4; ++r) {
        const int row = gm0 + wr * 64 + i * 16 + qd * 4 + r;
        out[(size_t)row * 512 + col] = acc[i][j][r] + bval;
      }
    }
}

// ---------------------------------------------------------------------------
extern "C" void kernel_launch(void* const* d_in, const int* in_sizes, int n_in,
                              void* d_out, int out_size, void* d_ws, size_t ws_size,
                              hipStream_t stream) {
  const float* x    = (const float*)d_in[0];
  const float* wqkv = (const float*)d_in[1];
  const float* wout = (const float*)d_in[2];
  const float* bout = (const float*)d_in[3];
  const float* cw   = (const float*)d_in[4];
  float* out = (float*)d_out;

  float* w = (float*)d_ws;
  float* q    = w;                       // [4,8,4096,64] fp32 (reused as oh)
  float* k    = w + 8388608;
  float* v    = w + 16777216;
  float* ql   = w + 25165824;
  float* kl   = ql + 524288;
  float* x2   = kl + 524288;             // [32,256,256]
  float* z0   = x2 + 2097152;
  float* z0t  = z0 + 2097152;
  float* z1   = z0t + 2097152;
  float* z1t  = z1 + 2097152;
  float* xz   = z1t + 2097152;
  float* xzt  = xz + 2097152;
  float* u1t  = xzt + 2097152;
  float* u2t  = u1t + 2097152;
  float* av   = u2t + 2097152;           // [32,256,64]
  float* w2t  = av + 524288;             // [32,64,256]
  float* marr = w2t + 524288;            // (unused this round)
  float* larr = marr + 8192;
  float* scal = larr + 8192;             // [2]
  short* wqkvT = (short*)(w + 46153732); // [1536,512] bf16
  short* woutT = (short*)(w + 46546948); // [512,512] bf16
  // aliases valid only AFTER the pinv loop (xz/xzt/u1t/u2t/z1/z1t are dead):
  short* kb16  = (short*)xz;             // [32,4096,64] bf16 (16 MB = xz+xzt)
  short* vT16  = (short*)u1t;            // [32,64,4096] bf16 (16 MB = u1t+u2t)
  float* opart = z1;                     // [4,32,256,64] fp32 (8 MB)
  float* mpart = z1t;                    // [4,32,256]
  float* lpart = z1t + 32768;            // [4,32,256]

  zero_scal<<<1, 64, 0, stream>>>(scal);
  transpose_bf16<<<dim3(48, 16), 256, 0, stream>>>(wqkv, wqkvT, 512, 1536);
  transpose_bf16<<<dim3(16, 16), 256, 0, stream>>>(wout, woutT, 512, 512);
  gemm_qkv_mfma<<<dim3(128, 12), 256, 0, stream>>>(x, wqkvT, q, k, v);
  lmk_mean<<<2048, 256, 0, stream>>>(q, k, ql, kl);
  sim2_softmax<<<512, 256, 0, stream>>>(ql, kl, x2);
  colrow_max<<<32, 256, 0, stream>>>(x2, scal);
  tscale2<<<8192, 256, 0, stream>>>(x2, scal, z0, z0t);

  float *zc = z0, *zct = z0t, *zn = z1, *znt = z1t;
  for (int it = 0; it < 6; ++it) {
    pinv_mfma<<<dim3(16, 32), 256, 0, stream>>>(x2, zct, x2, xz, xzt, 0.f, 1.f, 1, 1);
    pinv_mfma<<<dim3(16, 32), 256, 0, stream>>>(xz, xzt, xz, u1t, u1t, 7.f, -1.f, 0, 1);
    pinv_mfma<<<dim3(16, 32), 256, 0, stream>>>(xz, u1t, xz, u2t, u2t, 15.f, -1.f, 0, 1);
    pinv_mfma<<<dim3(16, 32), 256, 0, stream>>>(zc, u2t, zc, zn, znt, 3.25f, -0.25f, 1, 1);
    float* t;
    t = zc; zc = zn; zn = t;
    t = zct; zct = znt; znt = t;
  }
  // zc == z0 here; z1/z1t and xz/xzt/u1t/u2t are dead -> aliased buffers live.

  prep_kv<<<2048, 256, 0, stream>>>(k, v, kb16, vT16);
  attn3_flash<<<dim3(4, 4, 32), 256, 0, stream>>>(ql, kb16, vT16, opart, mpart, lpart);
  attn3_merge<<<2048, 256, 0, stream>>>(opart, mpart, lpart, av);
  zav_gemm_t<<<dim3(32, 4), 256, 0, stream>>>(zc, av, w2t);
  attn1_mfma<<<dim3(64, 32), 256, 0, stream>>>(q, kl, w2t, q /* in-place */);
  conv_res<<<32768, 256, 0, stream>>>(v, cw, q);
  gemm_out_mfma<<<dim3(128, 4), 256, 0, stream>>>(q, woutT, bout, out);
}

// Round 4
// 1062.594 us; speedup vs baseline: 2.1762x; 1.1427x over previous
//
#include <hip/hip_runtime.h>
#include <math.h>

// ---------------------------------------------------------------------------
// NystromAttention round 4: conv fused into attn1 epilogue; pinv XCD-swizzled
// grid + LDS-staged coalesced transposed writes.
// b=4 n=4096 dim=512 h=8 d=64 m=256, l=16, iters=6, conv k=33.
// MFMA 16x16x32_bf16 layouts (HW-verified per guide):
//   A: m=lane&15, k=(lane>>4)*8+j    B: n=lane&15, k=(lane>>4)*8+j
//   C/D: col=lane&15, row=(lane>>4)*4+reg
// ---------------------------------------------------------------------------

#define QKV_STRIDE 262144   // 4096*64 per (b,h)
#define LM_STRIDE 16384     // 256*64
#define MM_STRIDE 65536     // 256*256

typedef float f32x4 __attribute__((ext_vector_type(4)));
typedef short bf8 __attribute__((ext_vector_type(8)));   // 8 bf16 in 4 VGPRs
typedef short s4v __attribute__((ext_vector_type(4)));

__device__ __forceinline__ unsigned short f2bf_(float f) {
  unsigned u = __float_as_uint(f);
  u += 0x7FFFu + ((u >> 16) & 1u);   // RNE
  return (unsigned short)(u >> 16);
}
__device__ __forceinline__ float bf2f_(unsigned short h) {
  return __uint_as_float(((unsigned)h) << 16);
}
__device__ __forceinline__ bf8 pack8(const float4 a, const float4 b) {
  bf8 r;
  r[0] = (short)f2bf_(a.x); r[1] = (short)f2bf_(a.y);
  r[2] = (short)f2bf_(a.z); r[3] = (short)f2bf_(a.w);
  r[4] = (short)f2bf_(b.x); r[5] = (short)f2bf_(b.y);
  r[6] = (short)f2bf_(b.z); r[7] = (short)f2bf_(b.w);
  return r;
}

__global__ __launch_bounds__(256) void zero_scal(float* scal) {
  if (threadIdx.x < 2) scal[threadIdx.x] = 0.0f;
}

// ------------- transpose + fp32->bf16: dst[C][R] = bf16(src[R][C]) ----------
__global__ __launch_bounds__(256) void transpose_bf16(const float* __restrict__ src,
                                                      short* __restrict__ dst,
                                                      int R, int C) {
  __shared__ float T[32][33];
  const int t = threadIdx.x;
  const int c0 = blockIdx.x * 32, r0 = blockIdx.y * 32;
  const int tr = t >> 3, tc = (t & 7) << 2;
  float4 vsrc = *(const float4*)&src[(size_t)(r0 + tr) * C + c0 + tc];
  T[tr][tc + 0] = vsrc.x; T[tr][tc + 1] = vsrc.y;
  T[tr][tc + 2] = vsrc.z; T[tr][tc + 3] = vsrc.w;
  __syncthreads();
  s4v o;
  o[0] = (short)f2bf_(T[tc + 0][tr]);
  o[1] = (short)f2bf_(T[tc + 1][tr]);
  o[2] = (short)f2bf_(T[tc + 2][tr]);
  o[3] = (short)f2bf_(T[tc + 3][tr]);
  *(s4v*)&dst[(size_t)(c0 + tr) * R + r0 + tc] = o;
}

// ------------- qkv = x @ w_qkv via MFMA; scatter to q/k/v, q*=0.125 ---------
__global__ __launch_bounds__(256) void gemm_qkv_mfma(const float* __restrict__ x,
                                                     const short* __restrict__ wT,
                                                     float* __restrict__ q,
                                                     float* __restrict__ k,
                                                     float* __restrict__ v) {
  __shared__ short As[4096];  // 128x32 frag-order
  __shared__ short Bs[4096];
  const int tid = threadIdx.x;
  const int lane = tid & 63, w = tid >> 6;
  const int wr = w >> 1, wc = w & 1;
  const int gm0 = blockIdx.x * 128, gn0 = blockIdx.y * 128;
  const int mA0 = (tid >> 6) * 16 + (tid & 15), kA0 = ((tid >> 4) & 3) * 8;
  const int s1 = tid + 256;
  const int mA1 = (s1 >> 6) * 16 + (s1 & 15), kA1 = ((s1 >> 4) & 3) * 8;
  f32x4 acc[4][4];
#pragma unroll
  for (int i = 0; i < 4; ++i)
#pragma unroll
    for (int j = 0; j < 4; ++j) acc[i][j] = (f32x4){0.f, 0.f, 0.f, 0.f};
  for (int kt = 0; kt < 16; ++kt) {
    const int k0 = kt * 32;
    float4 a0 = *(const float4*)&x[(size_t)(gm0 + mA0) * 512 + k0 + kA0];
    float4 a1 = *(const float4*)&x[(size_t)(gm0 + mA0) * 512 + k0 + kA0 + 4];
    float4 a2 = *(const float4*)&x[(size_t)(gm0 + mA1) * 512 + k0 + kA1];
    float4 a3 = *(const float4*)&x[(size_t)(gm0 + mA1) * 512 + k0 + kA1 + 4];
    bf8 b0 = *(const bf8*)&wT[(size_t)(gn0 + mA0) * 512 + k0 + kA0];
    bf8 b1 = *(const bf8*)&wT[(size_t)(gn0 + mA1) * 512 + k0 + kA1];
    __syncthreads();
    *(bf8*)&As[tid * 8] = pack8(a0, a1);
    *(bf8*)&As[s1 * 8] = pack8(a2, a3);
    *(bf8*)&Bs[tid * 8] = b0;
    *(bf8*)&Bs[s1 * 8] = b1;
    __syncthreads();
    bf8 af[4], bf[4];
#pragma unroll
    for (int i = 0; i < 4; ++i) {
      af[i] = *(const bf8*)&As[((wr * 4 + i) * 64 + lane) * 8];
      bf[i] = *(const bf8*)&Bs[((wc * 4 + i) * 64 + lane) * 8];
    }
#pragma unroll
    for (int i = 0; i < 4; ++i)
#pragma unroll
      for (int j = 0; j < 4; ++j)
        acc[i][j] = __builtin_amdgcn_mfma_f32_16x16x32_bf16(af[i], bf[j], acc[i][j], 0, 0, 0);
  }
  const int which = blockIdx.y >> 2;  // 0:q 1:k 2:v
  float* dst = which == 0 ? q : (which == 1 ? k : v);
  const float scale = which == 0 ? 0.125f : 1.0f;
  const int qd = lane >> 4, c = lane & 15;
#pragma unroll
  for (int i = 0; i < 4; ++i) {
#pragma unroll
    for (int j = 0; j < 4; ++j) {
      const int col = gn0 + wc * 64 + j * 16 + c;
      const int head = (col >> 6) & 7, dd = col & 63;
#pragma unroll
      for (int r = 0; r < 4; ++r) {
        const int row = gm0 + wr * 64 + i * 16 + qd * 4 + r;
        const int b = row >> 12, seq = row & 4095;
        dst[(size_t)(b * 8 + head) * QKV_STRIDE + seq * 64 + dd] = acc[i][j][r] * scale;
      }
    }
  }
}

// ---------------- landmark means ------------------------------------------
__global__ __launch_bounds__(256) void lmk_mean(const float* __restrict__ q,
                                                const float* __restrict__ k,
                                                float* __restrict__ ql,
                                                float* __restrict__ kl) {
  const int g = blockIdx.x * 256 + threadIdx.x;
  const int dd = g & 63, mi = (g >> 6) & 255, bh = g >> 14;
  const size_t base = (size_t)bh * QKV_STRIDE + mi * 1024 + dd;
  float sq = 0.f, sk = 0.f;
#pragma unroll
  for (int jj = 0; jj < 16; ++jj) {
    sq += q[base + jj * 64];
    sk += k[base + jj * 64];
  }
  ql[g] = sq * 0.0625f;
  kl[g] = sk * 0.0625f;
}

// ------- prep: kb16[seq][d] = bf16(k);  vT16[d][seq] = bf16(v) --------------
__global__ __launch_bounds__(256) void prep_kv(const float* __restrict__ k,
                                               const float* __restrict__ v,
                                               short* __restrict__ kb16,
                                               short* __restrict__ vT16) {
  const int bh = blockIdx.x >> 6, s0 = (blockIdx.x & 63) * 64;
  __shared__ short Tv[64][68];
  const int tid = threadIdx.x;
  const int tr = tid >> 2, tc = (tid & 3) * 16;
  const size_t base = (size_t)bh * QKV_STRIDE + (size_t)(s0 + tr) * 64 + tc;
#pragma unroll
  for (int u = 0; u < 4; ++u) {
    float4 kk = *(const float4*)&k[base + u * 4];
    s4v ks;
    ks[0] = (short)f2bf_(kk.x); ks[1] = (short)f2bf_(kk.y);
    ks[2] = (short)f2bf_(kk.z); ks[3] = (short)f2bf_(kk.w);
    *(s4v*)&kb16[base + u * 4] = ks;
    float4 vv = *(const float4*)&v[base + u * 4];
    Tv[tr][tc + u * 4 + 0] = (short)f2bf_(vv.x);
    Tv[tr][tc + u * 4 + 1] = (short)f2bf_(vv.y);
    Tv[tr][tc + u * 4 + 2] = (short)f2bf_(vv.z);
    Tv[tr][tc + u * 4 + 3] = (short)f2bf_(vv.w);
  }
  __syncthreads();
  const int d = tid >> 2, sgrp = (tid & 3) * 16;
#pragma unroll
  for (int u = 0; u < 2; ++u) {
    bf8 o;
#pragma unroll
    for (int ii = 0; ii < 8; ++ii) o[ii] = Tv[sgrp + u * 8 + ii][d];
    *(bf8*)&vT16[(size_t)bh * QKV_STRIDE + (size_t)d * 4096 + s0 + sgrp + u * 8] = o;
  }
}

// ---------------- sim2 = ql @ kl^T, softmax -> x2 ---------------------------
__global__ __launch_bounds__(256) void sim2_softmax(const float* __restrict__ ql,
                                                    const float* __restrict__ kl,
                                                    float* __restrict__ x2) {
  const int blk = blockIdx.x;
  const int bh = blk >> 4, rg = blk & 15;
  __shared__ float Qs[16][64];
  __shared__ float Ks[64][68];
  __shared__ float S[16][257];
  __shared__ float red[16][17];
  __shared__ float rowinv[16];
  const int tid = threadIdx.x;
  const int r = tid >> 4, jc = tid & 15;
#pragma unroll
  for (int u = 0; u < 4; ++u) {
    int t2 = tid + u * 256;
    Qs[t2 >> 6][t2 & 63] =
        ql[(size_t)bh * LM_STRIDE + (rg * 16 + (t2 >> 6)) * 64 + (t2 & 63)];
  }
  for (int c = 0; c < 4; ++c) {
    __syncthreads();
#pragma unroll
    for (int u = 0; u < 4; ++u) {
      int t4 = tid + u * 256;
      int row = t4 >> 4, c4 = (t4 & 15) << 2;
      *(float4*)&Ks[row][c4] =
          *(const float4*)&kl[(size_t)bh * LM_STRIDE + (c * 64 + row) * 64 + c4];
    }
    __syncthreads();
#pragma unroll
    for (int s = 0; s < 4; ++s) {
      const int jj = jc + (s << 4);
      float acc = 0.f;
#pragma unroll
      for (int k4 = 0; k4 < 16; ++k4) {
        const float4 a = *(const float4*)&Qs[r][k4 << 2];
        const float4 bb = *(const float4*)&Ks[jj][k4 << 2];
        acc += a.x * bb.x + a.y * bb.y + a.z * bb.z + a.w * bb.w;
      }
      S[r][(c << 6) + jj] = acc;
    }
  }
  __syncthreads();
  float pm = -3.0e38f;
#pragma unroll
  for (int u = 0; u < 16; ++u) pm = fmaxf(pm, S[r][jc + (u << 4)]);
  red[r][jc] = pm;
  __syncthreads();
  float m = red[r][0];
#pragma unroll
  for (int u = 1; u < 16; ++u) m = fmaxf(m, red[r][u]);
  __syncthreads();
  float ps = 0.f;
#pragma unroll
  for (int u = 0; u < 16; ++u) {
    const int j = jc + (u << 4);
    const float e = __expf(S[r][j] - m);
    S[r][j] = e;
    ps += e;
  }
  red[r][jc] = ps;
  __syncthreads();
  if (jc == 0) {
    float sum = 0.f;
#pragma unroll
    for (int u = 0; u < 16; ++u) sum += red[r][u];
    rowinv[r] = 1.0f / sum;
  }
  __syncthreads();
  for (int idx = tid; idx < 4096; idx += 256) {
    const int rr = idx >> 8, j = idx & 255;
    x2[(size_t)bh * MM_STRIDE + (rg * 16 + rr) * 256 + j] = S[rr][j] * rowinv[rr];
  }
}

// ---------------- global max of col/row abs-sums ----------------------------
__global__ __launch_bounds__(256) void colrow_max(const float* __restrict__ x2,
                                                  float* __restrict__ scal) {
  const int bh = blockIdx.x;
  const int tid = threadIdx.x;
  const float* xb = x2 + (size_t)bh * MM_STRIDE;
  float cs = 0.f, rs = 0.f;
  for (int j = 0; j < 256; ++j) cs += fabsf(xb[tid * 256 + j]);
  for (int i = 0; i < 256; ++i) rs += fabsf(xb[i * 256 + tid]);
  __shared__ float rc[256], rr[256];
  rc[tid] = cs; rr[tid] = rs;
  __syncthreads();
  for (int st = 128; st > 0; st >>= 1) {
    if (tid < st) {
      rc[tid] = fmaxf(rc[tid], rc[tid + st]);
      rr[tid] = fmaxf(rr[tid], rr[tid + st]);
    }
    __syncthreads();
  }
  if (tid == 0) {
    atomicMax((int*)&scal[0], __float_as_int(rc[0]));
    atomicMax((int*)&scal[1], __float_as_int(rr[0]));
  }
}

// --------- z0 = x2^T/(cmax*rmax), z0t = x2/(cmax*rmax) ----------------------
__global__ __launch_bounds__(256) void tscale2(const float* __restrict__ x2,
                                               const float* __restrict__ scal,
                                               float* __restrict__ z0,
                                               float* __restrict__ z0t) {
  const int g = blockIdx.x * 256 + threadIdx.x;
  const int j = g & 255, i = (g >> 8) & 255, bh = g >> 16;
  const float inv = 1.0f / (scal[0] * scal[1]);
  const float val = x2[g] * inv;      // x2[bh][i][j]
  z0t[g] = val;
  z0[(size_t)bh * MM_STRIDE + j * 256 + i] = val;
}

// --------- split-bf16 batched 256^3: C = alpha*E + beta*(A@B) ---------------
// Grid: 512 1-D blocks, XCD-swizzled so one batch's 16 tiles share an XCD.
// CT written via LDS-staged transpose (coalesced rows).
__global__ __launch_bounds__(256) void pinv_mfma(const float* __restrict__ A,
                                                 const float* __restrict__ BT,
                                                 const float* __restrict__ E,
                                                 float* __restrict__ C,
                                                 float* __restrict__ CT,
                                                 float alpha, float beta,
                                                 int wantC, int wantT) {
  __shared__ short Ahi[2048], Alo[2048], Bhi[2048], Blo[2048];  // 64x32 each
  __shared__ float Tbuf[64 * 68];
  const int tid = threadIdx.x;
  const int lane = tid & 63, w = tid >> 6;
  // swizzle: all 16 tiles of a batch land on one XCD (bid%8 = XCD heuristic)
  const int bid = blockIdx.x;
  const int xcd = bid & 7, y = bid >> 3;
  const int t16 = y & 15, bgrp = y >> 4;
  const int batch = bgrp * 8 + xcd;
  const int tm = t16 >> 2, tn = t16 & 3;
  const float* Ab = A + (size_t)batch * MM_STRIDE;
  const float* BTb = BT + (size_t)batch * MM_STRIDE;
  const float* Eb = E + (size_t)batch * MM_STRIDE;
  const int ml = (tid >> 6) * 16 + (tid & 15), koff = ((tid >> 4) & 3) * 8;
  f32x4 acc[4];
#pragma unroll
  for (int j = 0; j < 4; ++j) acc[j] = (f32x4){0.f, 0.f, 0.f, 0.f};
  for (int kt = 0; kt < 8; ++kt) {
    const int k0 = kt * 32;
    float4 a0 = *(const float4*)&Ab[(size_t)(tm * 64 + ml) * 256 + k0 + koff];
    float4 a1 = *(const float4*)&Ab[(size_t)(tm * 64 + ml) * 256 + k0 + koff + 4];
    float4 b0 = *(const float4*)&BTb[(size_t)(tn * 64 + ml) * 256 + k0 + koff];
    float4 b1 = *(const float4*)&BTb[(size_t)(tn * 64 + ml) * 256 + k0 + koff + 4];
    __syncthreads();
    {
      bf8 hi, lo;
      const float fa[8] = {a0.x, a0.y, a0.z, a0.w, a1.x, a1.y, a1.z, a1.w};
#pragma unroll
      for (int e = 0; e < 8; ++e) {
        unsigned short h = f2bf_(fa[e]);
        hi[e] = (short)h;
        lo[e] = (short)f2bf_(fa[e] - bf2f_(h));
      }
      *(bf8*)&Ahi[tid * 8] = hi;
      *(bf8*)&Alo[tid * 8] = lo;
      const float fb[8] = {b0.x, b0.y, b0.z, b0.w, b1.x, b1.y, b1.z, b1.w};
#pragma unroll
      for (int e = 0; e < 8; ++e) {
        unsigned short h = f2bf_(fb[e]);
        hi[e] = (short)h;
        lo[e] = (short)f2bf_(fb[e] - bf2f_(h));
      }
      *(bf8*)&Bhi[tid * 8] = hi;
      *(bf8*)&Blo[tid * 8] = lo;
    }
    __syncthreads();
    bf8 ah = *(const bf8*)&Ahi[(w * 64 + lane) * 8];
    bf8 al = *(const bf8*)&Alo[(w * 64 + lane) * 8];
#pragma unroll
    for (int j = 0; j < 4; ++j) {
      bf8 bh = *(const bf8*)&Bhi[(j * 64 + lane) * 8];
      bf8 bl = *(const bf8*)&Blo[(j * 64 + lane) * 8];
      acc[j] = __builtin_amdgcn_mfma_f32_16x16x32_bf16(ah, bh, acc[j], 0, 0, 0);
      acc[j] = __builtin_amdgcn_mfma_f32_16x16x32_bf16(ah, bl, acc[j], 0, 0, 0);
      acc[j] = __builtin_amdgcn_mfma_f32_16x16x32_bf16(al, bh, acc[j], 0, 0, 0);
    }
  }
  float* Cb = C + (size_t)batch * MM_STRIDE;
  float* CTb = CT + (size_t)batch * MM_STRIDE;
  const int qd = lane >> 4, c = lane & 15;
  // epilogue: val = alpha*E + beta*acc; optional C write (coalesced-enough),
  // CT via LDS transpose stage.
  float vals[4][4];
#pragma unroll
  for (int j = 0; j < 4; ++j) {
    const int col = tn * 64 + j * 16 + c;
#pragma unroll
    for (int r = 0; r < 4; ++r) {
      const int row = tm * 64 + w * 16 + qd * 4 + r;
      vals[j][r] = alpha * Eb[(size_t)row * 256 + col] + beta * acc[j][r];
      if (wantC) Cb[(size_t)row * 256 + col] = vals[j][r];
    }
  }
  if (wantT) {
    __syncthreads();
#pragma unroll
    for (int j = 0; j < 4; ++j)
#pragma unroll
      for (int r = 0; r < 4; ++r)
        Tbuf[(j * 16 + c) * 68 + w * 16 + qd * 4 + r] = vals[j][r];
    __syncthreads();
    const int ctr = tid >> 2, seg = (tid & 3) * 16;
#pragma unroll
    for (int u = 0; u < 4; ++u) {
      float4 o = *(const float4*)&Tbuf[ctr * 68 + seg + u * 4];
      *(float4*)&CTb[(size_t)(tn * 64 + ctr) * 256 + tm * 64 + seg + u * 4] = o;
    }
  }
}

// ---- attn3 flash: O_part = exp(ql@k^T - m) @ v over a 1024-key chunk -------
__global__ __launch_bounds__(256) void attn3_flash(const float* __restrict__ ql,
                                                   const short* __restrict__ kb16,
                                                   const short* __restrict__ vT16,
                                                   float* __restrict__ opart,
                                                   float* __restrict__ mpart,
                                                   float* __restrict__ lpart) {
  const int kc = blockIdx.x;   // key chunk 0..3 (1024 keys each)
  const int rt = blockIdx.y;   // row tile 0..3 (64 rows each)
  const int bh = blockIdx.z;   // 0..31
  __shared__ short Pa[16384];  // 64 rows x 256 keys, A-frag order
  __shared__ float redM[4][64], redS[4][64];
  __shared__ float mRow[64], lRow[64], alphaRow[64];
  const int tid = threadIdx.x, lane = tid & 63, w = tid >> 6;
  const int qd = lane >> 4, c = lane & 15;
  const int r0 = rt * 64;
  const float* qlp = ql + (size_t)bh * LM_STRIDE;
  const short* kp = kb16 + (size_t)bh * QKV_STRIDE;
  const short* vp = vT16 + (size_t)bh * QKV_STRIDE;
  bf8 af[2][4];
#pragma unroll
  for (int st = 0; st < 2; ++st)
#pragma unroll
    for (int i = 0; i < 4; ++i) {
      float4 x0 = *(const float4*)&qlp[(size_t)(r0 + i * 16 + c) * 64 + st * 32 + qd * 8];
      float4 x1 = *(const float4*)&qlp[(size_t)(r0 + i * 16 + c) * 64 + st * 32 + qd * 8 + 4];
      af[st][i] = pack8(x0, x1);
    }
  if (tid < 64) { mRow[tid] = -3.0e38f; lRow[tid] = 0.f; }
  f32x4 accO[4];
#pragma unroll
  for (int nb = 0; nb < 4; ++nb) accO[nb] = (f32x4){0.f, 0.f, 0.f, 0.f};
  __syncthreads();
  for (int it = 0; it < 4; ++it) {
    const int kb0 = kc * 1024 + it * 256;
    f32x4 acc[4][4];
#pragma unroll
    for (int i = 0; i < 4; ++i)
#pragma unroll
      for (int j = 0; j < 4; ++j) acc[i][j] = (f32x4){0.f, 0.f, 0.f, 0.f};
#pragma unroll
    for (int st = 0; st < 2; ++st) {
      bf8 bfk[4];
#pragma unroll
      for (int j = 0; j < 4; ++j)
        bfk[j] = *(const bf8*)&kp[(size_t)(kb0 + w * 64 + j * 16 + c) * 64 + st * 32 + qd * 8];
#pragma unroll
      for (int i = 0; i < 4; ++i)
#pragma unroll
        for (int j = 0; j < 4; ++j)
          acc[i][j] = __builtin_amdgcn_mfma_f32_16x16x32_bf16(af[st][i], bfk[j], acc[i][j], 0, 0, 0);
    }
#pragma unroll
    for (int i = 0; i < 4; ++i)
#pragma unroll
      for (int r = 0; r < 4; ++r) {
        float m0 = fmaxf(fmaxf(acc[i][0][r], acc[i][1][r]),
                         fmaxf(acc[i][2][r], acc[i][3][r]));
        m0 = fmaxf(m0, __shfl_xor(m0, 1));
        m0 = fmaxf(m0, __shfl_xor(m0, 2));
        m0 = fmaxf(m0, __shfl_xor(m0, 4));
        m0 = fmaxf(m0, __shfl_xor(m0, 8));
        if (c == 0) redM[w][i * 16 + qd * 4 + r] = m0;
      }
    __syncthreads();
    if (tid < 64) {
      float mN = fmaxf(fmaxf(redM[0][tid], redM[1][tid]),
                       fmaxf(redM[2][tid], redM[3][tid]));
      mN = fmaxf(mN, mRow[tid]);
      const float a = __expf(mRow[tid] - mN);
      alphaRow[tid] = a;
      mRow[tid] = mN;
      lRow[tid] *= a;
    }
    __syncthreads();
#pragma unroll
    for (int r = 0; r < 4; ++r) {
      const float a = alphaRow[w * 16 + qd * 4 + r];
#pragma unroll
      for (int nb = 0; nb < 4; ++nb) accO[nb][r] *= a;
    }
#pragma unroll
    for (int i = 0; i < 4; ++i)
#pragma unroll
      for (int r = 0; r < 4; ++r) {
        const int row = i * 16 + qd * 4 + r;
        const float mrow = mRow[row];
        float s = 0.f;
#pragma unroll
        for (int j = 0; j < 4; ++j) {
          const float e = __expf(acc[i][j][r] - mrow);
          acc[i][j][r] = e;
          s += e;
        }
        s += __shfl_xor(s, 1);
        s += __shfl_xor(s, 2);
        s += __shfl_xor(s, 4);
        s += __shfl_xor(s, 8);
        if (c == 0) redS[w][row] = s;
      }
    __syncthreads();
    if (tid < 64)
      lRow[tid] += redS[0][tid] + redS[1][tid] + redS[2][tid] + redS[3][tid];
#pragma unroll
    for (int i = 0; i < 4; ++i)
#pragma unroll
      for (int r = 0; r < 4; ++r) {
        const int row = i * 16 + qd * 4 + r;
#pragma unroll
        for (int j = 0; j < 4; ++j) {
          const int col = w * 64 + j * 16 + c;
          const int kbk = col >> 5;
          const int lane2 = (row & 15) + 16 * ((col >> 3) & 3);
          Pa[((kbk * 4 + i) * 64 + lane2) * 8 + (col & 7)] = (short)f2bf_(acc[i][j][r]);
        }
      }
    __syncthreads();
#pragma unroll
    for (int kbk = 0; kbk < 8; ++kbk) {
      bf8 ap = *(const bf8*)&Pa[((kbk * 4 + w) * 64 + lane) * 8];
#pragma unroll
      for (int nb = 0; nb < 4; ++nb) {
        bf8 bv = *(const bf8*)&vp[(size_t)(nb * 16 + c) * 4096 + kb0 + kbk * 32 + qd * 8];
        accO[nb] = __builtin_amdgcn_mfma_f32_16x16x32_bf16(ap, bv, accO[nb], 0, 0, 0);
      }
    }
    __syncthreads();
  }
  const size_t ob = ((size_t)kc * 32 + bh) * 256 + r0;
#pragma unroll
  for (int nb = 0; nb < 4; ++nb)
#pragma unroll
    for (int r = 0; r < 4; ++r)
      opart[(ob + w * 16 + qd * 4 + r) * 64 + nb * 16 + c] = accO[nb][r];
  if (tid < 64) {
    mpart[ob + tid] = mRow[tid];
    lpart[ob + tid] = lRow[tid];
  }
}

// ---------------- merge the 4 key-chunk partials -> av ----------------------
__global__ __launch_bounds__(256) void attn3_merge(const float* __restrict__ opart,
                                                   const float* __restrict__ mpart,
                                                   const float* __restrict__ lpart,
                                                   float* __restrict__ av) {
  const int g = blockIdx.x * 256 + threadIdx.x;   // 524288 = 32*256*64
  const int d = g & 63;
  const int idx = g >> 6;                          // bh*256+row
  const float m0 = mpart[idx], m1 = mpart[8192 + idx],
              m2 = mpart[16384 + idx], m3 = mpart[24576 + idx];
  const float mx = fmaxf(fmaxf(m0, m1), fmaxf(m2, m3));
  const float w0 = __expf(m0 - mx), w1 = __expf(m1 - mx),
              w2 = __expf(m2 - mx), w3 = __expf(m3 - mx);
  const float l = lpart[idx] * w0 + lpart[8192 + idx] * w1 +
                  lpart[16384 + idx] * w2 + lpart[24576 + idx] * w3;
  const float o = opart[(size_t)idx * 64 + d] * w0 +
                  opart[524288 + (size_t)idx * 64 + d] * w1 +
                  opart[1048576 + (size_t)idx * 64 + d] * w2 +
                  opart[1572864 + (size_t)idx * 64 + d] * w3;
  av[g] = o / l;
}

// ---------------- w2^T = (z_final @ av)^T : stores w2t[d][i] ----------------
__global__ __launch_bounds__(256) void zav_gemm_t(const float* __restrict__ z,
                                                  const float* __restrict__ av,
                                                  float* __restrict__ w2t) {
  const int bh = blockIdx.x;
  const int rq = blockIdx.y;
  __shared__ float Av[256][64];
  const int tid = threadIdx.x;
#pragma unroll
  for (int u = 0; u < 16; ++u) {
    int t4 = tid + u * 256;
    int row = t4 >> 4, c4 = (t4 & 15) << 2;
    *(float4*)&Av[row][c4] = *(const float4*)&av[(size_t)bh * LM_STRIDE + row * 64 + c4];
  }
  __syncthreads();
  const int d = tid & 63, rg4 = tid >> 6;
  for (int s = 0; s < 16; ++s) {
    const int i = rq * 64 + s * 4 + rg4;
    const float* zr = z + (size_t)bh * MM_STRIDE + i * 256;
    float acc = 0.f;
#pragma unroll 8
    for (int j = 0; j < 256; ++j) acc += zr[j] * Av[j][d];
    w2t[(size_t)bh * LM_STRIDE + d * 256 + i] = acc;
  }
}

// ---- attn1+conv: oh = softmax(q@kl^T)@w2 + depthwise_conv(v), in-place -----
__global__ __launch_bounds__(256) void attn1_conv_mfma(const float* __restrict__ q,
                                                       const float* __restrict__ kl,
                                                       const float* __restrict__ w2t,
                                                       const float* __restrict__ v,
                                                       const float* __restrict__ cw,
                                                       float* __restrict__ oh) {
  __shared__ short Pa[16384];               // 64x256 bf16 in A-frag order
  __shared__ float redM[4][64], redS[4][64];
  __shared__ float rowM[64], rowI[64];
  __shared__ float Vc[96 * 68];             // v rows [r0-16, r0+80), stride 68
  __shared__ float cwS[33];
  const int tid = threadIdx.x;
  const int lane = tid & 63, w = tid >> 6;
  const int qd = lane >> 4, c = lane & 15;
  const int r0 = blockIdx.x * 64;
  const int bh = blockIdx.y;
  const float* qp = q + (size_t)bh * QKV_STRIDE;
  const float* klp = kl + (size_t)bh * LM_STRIDE;
  const float* w2p = w2t + (size_t)bh * LM_STRIDE;
  const float* vp = v + (size_t)bh * QKV_STRIDE;

  if (tid < 33) cwS[tid] = cw[(bh & 7) * 33 + tid];
  // load v window into LDS (zero-padded at sequence edges)
#pragma unroll
  for (int u = 0; u < 6; ++u) {
    const int slot = u * 256 + tid;            // 1536 slots = 96 rows x 16 f4
    const int row = slot >> 4, c4 = (slot & 15) * 4;
    const int gr = r0 - 16 + row;
    float4 val = (gr >= 0 && gr < 4096)
                     ? *(const float4*)&vp[(size_t)gr * 64 + c4]
                     : make_float4(0.f, 0.f, 0.f, 0.f);
    Vc[row * 68 + c4 + 0] = val.x; Vc[row * 68 + c4 + 1] = val.y;
    Vc[row * 68 + c4 + 2] = val.z; Vc[row * 68 + c4 + 3] = val.w;
  }

  f32x4 acc[4][4];
#pragma unroll
  for (int i = 0; i < 4; ++i)
#pragma unroll
    for (int j = 0; j < 4; ++j) acc[i][j] = (f32x4){0.f, 0.f, 0.f, 0.f};
#pragma unroll
  for (int st = 0; st < 2; ++st) {
    const int k0 = st * 32 + qd * 8;
    bf8 af[4], bf[4];
#pragma unroll
    for (int i = 0; i < 4; ++i) {
      float4 x0 = *(const float4*)&qp[(size_t)(r0 + i * 16 + c) * 64 + k0];
      float4 x1 = *(const float4*)&qp[(size_t)(r0 + i * 16 + c) * 64 + k0 + 4];
      af[i] = pack8(x0, x1);
      float4 y0 = *(const float4*)&klp[(size_t)(w * 64 + i * 16 + c) * 64 + k0];
      float4 y1 = *(const float4*)&klp[(size_t)(w * 64 + i * 16 + c) * 64 + k0 + 4];
      bf[i] = pack8(y0, y1);
    }
#pragma unroll
    for (int i = 0; i < 4; ++i)
#pragma unroll
      for (int j = 0; j < 4; ++j)
        acc[i][j] = __builtin_amdgcn_mfma_f32_16x16x32_bf16(af[i], bf[j], acc[i][j], 0, 0, 0);
  }
#pragma unroll
  for (int i = 0; i < 4; ++i)
#pragma unroll
    for (int r = 0; r < 4; ++r) {
      float m0 = fmaxf(fmaxf(acc[i][0][r], acc[i][1][r]),
                       fmaxf(acc[i][2][r], acc[i][3][r]));
      m0 = fmaxf(m0, __shfl_xor(m0, 1));
      m0 = fmaxf(m0, __shfl_xor(m0, 2));
      m0 = fmaxf(m0, __shfl_xor(m0, 4));
      m0 = fmaxf(m0, __shfl_xor(m0, 8));
      if (c == 0) redM[w][i * 16 + qd * 4 + r] = m0;
    }
  __syncthreads();
  if (tid < 64)
    rowM[tid] = fmaxf(fmaxf(redM[0][tid], redM[1][tid]),
                      fmaxf(redM[2][tid], redM[3][tid]));
  __syncthreads();
#pragma unroll
  for (int i = 0; i < 4; ++i)
#pragma unroll
    for (int r = 0; r < 4; ++r) {
      const float mrow = rowM[i * 16 + qd * 4 + r];
      float s = 0.f;
#pragma unroll
      for (int j = 0; j < 4; ++j) {
        const float e = __expf(acc[i][j][r] - mrow);
        acc[i][j][r] = e;
        s += e;
      }
      s += __shfl_xor(s, 1);
      s += __shfl_xor(s, 2);
      s += __shfl_xor(s, 4);
      s += __shfl_xor(s, 8);
      if (c == 0) redS[w][i * 16 + qd * 4 + r] = s;
    }
  __syncthreads();
  if (tid < 64)
    rowI[tid] = 1.0f / (redS[0][tid] + redS[1][tid] + redS[2][tid] + redS[3][tid]);
  __syncthreads();
#pragma unroll
  for (int i = 0; i < 4; ++i)
#pragma unroll
    for (int r = 0; r < 4; ++r) {
      const int row = i * 16 + qd * 4 + r;
      const float inv = rowI[row];
#pragma unroll
      for (int j = 0; j < 4; ++j) {
        const int col = w * 64 + j * 16 + c;
        const short val = (short)f2bf_(acc[i][j][r] * inv);
        const int kb = col >> 5;
        const int lane2 = (row & 15) + 16 * ((col >> 3) & 3);
        Pa[((kb * 4 + i) * 64 + lane2) * 8 + (col & 7)] = val;
      }
    }
  __syncthreads();
  f32x4 accO[4];
#pragma unroll
  for (int nb = 0; nb < 4; ++nb) accO[nb] = (f32x4){0.f, 0.f, 0.f, 0.f};
  for (int kb = 0; kb < 8; ++kb) {
    bf8 ap = *(const bf8*)&Pa[((kb * 4 + w) * 64 + lane) * 8];
#pragma unroll
    for (int nb = 0; nb < 4; ++nb) {
      float4 y0 = *(const float4*)&w2p[(size_t)(nb * 16 + c) * 256 + kb * 32 + qd * 8];
      float4 y1 = *(const float4*)&w2p[(size_t)(nb * 16 + c) * 256 + kb * 32 + qd * 8 + 4];
      bf8 bfr = pack8(y0, y1);
      accO[nb] = __builtin_amdgcn_mfma_f32_16x16x32_bf16(ap, bfr, accO[nb], 0, 0, 0);
    }
  }
  // + depthwise conv residual from LDS window
  float* ohp = oh + (size_t)bh * QKV_STRIDE;
#pragma unroll
  for (int nb = 0; nb < 4; ++nb) {
    const int d = nb * 16 + c;
#pragma unroll
    for (int r = 0; r < 4; ++r) {
      const int rl = w * 16 + qd * 4 + r;     // 0..63 within tile
      float cacc = 0.f;
#pragma unroll
      for (int t = 0; t < 33; ++t) cacc += cwS[t] * Vc[(rl + t) * 68 + d];
      ohp[(size_t)(r0 + rl) * 64 + d] = accO[nb][r] + cacc;
    }
  }
}

// ---------------- out = concat_heads(oh) @ w_out + b_out (MFMA) -------------
__global__ __launch_bounds__(256) void gemm_out_mfma(const float* __restrict__ oh,
                                                     const short* __restrict__ wT,
                                                     const float* __restrict__ bias,
                                                     float* __restrict__ out) {
  __shared__ short As[4096];
  __shared__ short Bs[4096];
  const int tid = threadIdx.x;
  const int lane = tid & 63, w = tid >> 6;
  const int wr = w >> 1, wc = w & 1;
  const int gm0 = blockIdx.x * 128, gn0 = blockIdx.y * 128;
  const int mA0 = (tid >> 6) * 16 + (tid & 15), kA0 = ((tid >> 4) & 3) * 8;
  const int s1 = tid + 256;
  const int mA1 = (s1 >> 6) * 16 + (s1 & 15), kA1 = ((s1 >> 4) & 3) * 8;
  const int b0r = (gm0 + mA0) >> 12, seq0 = (gm0 + mA0) & 4095;
  const int b1r = (gm0 + mA1) >> 12, seq1 = (gm0 + mA1) & 4095;
  f32x4 acc[4][4];
#pragma unroll
  for (int i = 0; i < 4; ++i)
#pragma unroll
    for (int j = 0; j < 4; ++j) acc[i][j] = (f32x4){0.f, 0.f, 0.f, 0.f};
  for (int kt = 0; kt < 16; ++kt) {
    const int k0 = kt * 32;
    const int ka = k0 + kA0, kb = k0 + kA1;
    float4 a0 = *(const float4*)&oh[(size_t)(b0r * 8 + (ka >> 6)) * QKV_STRIDE + seq0 * 64 + (ka & 63)];
    float4 a1 = *(const float4*)&oh[(size_t)(b0r * 8 + (ka >> 6)) * QKV_STRIDE + seq0 * 64 + (ka & 63) + 4];
    float4 a2 = *(const float4*)&oh[(size_t)(b1r * 8 + (kb >> 6)) * QKV_STRIDE + seq1 * 64 + (kb & 63)];
    float4 a3 = *(const float4*)&oh[(size_t)(b1r * 8 + (kb >> 6)) * QKV_STRIDE + seq1 * 64 + (kb & 63) + 4];
    bf8 bb0 = *(const bf8*)&wT[(size_t)(gn0 + mA0) * 512 + ka];
    bf8 bb1 = *(const bf8*)&wT[(size_t)(gn0 + mA1) * 512 + kb];
    __syncthreads();
    *(bf8*)&As[tid * 8] = pack8(a0, a1);
    *(bf8*)&As[s1 * 8] = pack8(a2, a3);
    *(bf8*)&Bs[tid * 8] = bb0;
    *(bf8*)&Bs[s1 * 8] = bb1;
    __syncthreads();
    bf8 af[4], bfr[4];
#pragma unroll
    for (int i = 0; i < 4; ++i) {
      af[i] = *(const bf8*)&As[((wr * 4 + i) * 64 + lane) * 8];
      bfr[i] = *(const bf8*)&Bs[((wc * 4 + i) * 64 + lane) * 8];
    }
#pragma unroll
    for (int i = 0; i < 4; ++i)
#pragma unroll
      for (int j = 0; j < 4; ++j)
        acc[i][j] = __builtin_amdgcn_mfma_f32_16x16x32_bf16(af[i], bfr[j], acc[i][j], 0, 0, 0);
  }
  const int qd = lane >> 4, c = lane & 15;
#pragma unroll
  for (int i = 0; i < 4; ++i)
#pragma unroll
    for (int j = 0; j < 4; ++j) {
      const int col = gn0 + wc * 64 + j * 16 + c;
      const float bval = bias[col];
#pragma unroll
      for (int r = 0; r < 4; ++r) {
        const int row = gm0 + wr * 64 + i * 16 + qd * 4 + r;
        out[(size_t)row * 512 + col] = acc[i][j][r] + bval;
      }
    }
}

// ---------------------------------------------------------------------------
extern "C" void kernel_launch(void* const* d_in, const int* in_sizes, int n_in,
                              void* d_out, int out_size, void* d_ws, size_t ws_size,
                              hipStream_t stream) {
  const float* x    = (const float*)d_in[0];
  const float* wqkv = (const float*)d_in[1];
  const float* wout = (const float*)d_in[2];
  const float* bout = (const float*)d_in[3];
  const float* cw   = (const float*)d_in[4];
  float* out = (float*)d_out;

  float* w = (float*)d_ws;
  float* q    = w;                       // [4,8,4096,64] fp32 (reused as oh)
  float* k    = w + 8388608;
  float* v    = w + 16777216;
  float* ql   = w + 25165824;
  float* kl   = ql + 524288;
  float* x2   = kl + 524288;             // [32,256,256]
  float* z0   = x2 + 2097152;
  float* z0t  = z0 + 2097152;
  float* z1   = z0t + 2097152;
  float* z1t  = z1 + 2097152;
  float* xz   = z1t + 2097152;
  float* xzt  = xz + 2097152;
  float* u1t  = xzt + 2097152;
  float* u2t  = u1t + 2097152;
  float* av   = u2t + 2097152;           // [32,256,64]
  float* w2t  = av + 524288;             // [32,64,256]
  float* marr = w2t + 524288;
  float* larr = marr + 8192;
  float* scal = larr + 8192;             // [2]
  short* wqkvT = (short*)(w + 46153732); // [1536,512] bf16
  short* woutT = (short*)(w + 46546948); // [512,512] bf16
  // aliases valid only AFTER the pinv loop:
  short* kb16  = (short*)xz;             // [32,4096,64] bf16
  short* vT16  = (short*)u1t;            // [32,64,4096] bf16
  float* opart = z1;                     // [4,32,256,64] fp32
  float* mpart = z1t;                    // [4,32,256]
  float* lpart = z1t + 32768;            // [4,32,256]

  zero_scal<<<1, 64, 0, stream>>>(scal);
  transpose_bf16<<<dim3(48, 16), 256, 0, stream>>>(wqkv, wqkvT, 512, 1536);
  transpose_bf16<<<dim3(16, 16), 256, 0, stream>>>(wout, woutT, 512, 512);
  gemm_qkv_mfma<<<dim3(128, 12), 256, 0, stream>>>(x, wqkvT, q, k, v);
  lmk_mean<<<2048, 256, 0, stream>>>(q, k, ql, kl);
  sim2_softmax<<<512, 256, 0, stream>>>(ql, kl, x2);
  colrow_max<<<32, 256, 0, stream>>>(x2, scal);
  tscale2<<<8192, 256, 0, stream>>>(x2, scal, z0, z0t);

  float *zc = z0, *zct = z0t, *zn = z1, *znt = z1t;
  for (int it = 0; it < 6; ++it) {
    pinv_mfma<<<512, 256, 0, stream>>>(x2, zct, x2, xz, xzt, 0.f, 1.f, 1, 1);
    pinv_mfma<<<512, 256, 0, stream>>>(xz, xzt, xz, u1t, u1t, 7.f, -1.f, 0, 1);
    pinv_mfma<<<512, 256, 0, stream>>>(xz, u1t, xz, u2t, u2t, 15.f, -1.f, 0, 1);
    pinv_mfma<<<512, 256, 0, stream>>>(zc, u2t, zc, zn, znt, 3.25f, -0.25f, 1, 1);
    float* t;
    t = zc; zc = zn; zn = t;
    t = zct; zct = znt; znt = t;
  }
  // zc == z0 here; z1/z1t and xz/xzt/u1t/u2t are dead -> aliased buffers live.

  prep_kv<<<2048, 256, 0, stream>>>(k, v, kb16, vT16);
  attn3_flash<<<dim3(4, 4, 32), 256, 0, stream>>>(ql, kb16, vT16, opart, mpart, lpart);
  attn3_merge<<<2048, 256, 0, stream>>>(opart, mpart, lpart, av);
  zav_gemm_t<<<dim3(32, 4), 256, 0, stream>>>(zc, av, w2t);
  attn1_conv_mfma<<<dim3(64, 32), 256, 0, stream>>>(q, kl, w2t, v, cw, q /* in-place */);
  gemm_out_mfma<<<dim3(128, 4), 256, 0, stream>>>(q, woutT, bout, out);
}

// Round 5
// 910.980 us; speedup vs baseline: 2.5384x; 1.1664x over previous
//
#include <hip/hip_runtime.h>
#include <math.h>

// ---------------------------------------------------------------------------
// NystromAttention round 5: conv as MFMA inside attn1; bf16 dataflow end-to-end
// (q/k/vT/oh/kl/w2 stored bf16; prep_kv eliminated).
// b=4 n=4096 dim=512 h=8 d=64 m=256, l=16, iters=6, conv k=33.
// MFMA 16x16x32_bf16 layouts (HW-verified per guide):
//   A: m=lane&15, k=(lane>>4)*8+j    B: n=lane&15, k=(lane>>4)*8+j
//   C/D: col=lane&15, row=(lane>>4)*4+reg
// ---------------------------------------------------------------------------

#define QKV_STRIDE 262144   // 4096*64 per (b,h)
#define LM_STRIDE 16384     // 256*64
#define MM_STRIDE 65536     // 256*256

typedef float f32x4 __attribute__((ext_vector_type(4)));
typedef short bf8 __attribute__((ext_vector_type(8)));   // 8 bf16 in 4 VGPRs
typedef short s4v __attribute__((ext_vector_type(4)));

__device__ __forceinline__ unsigned short f2bf_(float f) {
  unsigned u = __float_as_uint(f);
  u += 0x7FFFu + ((u >> 16) & 1u);   // RNE
  return (unsigned short)(u >> 16);
}
__device__ __forceinline__ float bf2f_(unsigned short h) {
  return __uint_as_float(((unsigned)h) << 16);
}
__device__ __forceinline__ bf8 pack8(const float4 a, const float4 b) {
  bf8 r;
  r[0] = (short)f2bf_(a.x); r[1] = (short)f2bf_(a.y);
  r[2] = (short)f2bf_(a.z); r[3] = (short)f2bf_(a.w);
  r[4] = (short)f2bf_(b.x); r[5] = (short)f2bf_(b.y);
  r[6] = (short)f2bf_(b.z); r[7] = (short)f2bf_(b.w);
  return r;
}

__global__ __launch_bounds__(256) void zero_scal(float* scal) {
  if (threadIdx.x < 2) scal[threadIdx.x] = 0.0f;
}

// ------------- transpose + fp32->bf16: dst[C][R] = bf16(src[R][C]) ----------
__global__ __launch_bounds__(256) void transpose_bf16(const float* __restrict__ src,
                                                      short* __restrict__ dst,
                                                      int R, int C) {
  __shared__ float T[32][33];
  const int t = threadIdx.x;
  const int c0 = blockIdx.x * 32, r0 = blockIdx.y * 32;
  const int tr = t >> 3, tc = (t & 7) << 2;
  float4 vsrc = *(const float4*)&src[(size_t)(r0 + tr) * C + c0 + tc];
  T[tr][tc + 0] = vsrc.x; T[tr][tc + 1] = vsrc.y;
  T[tr][tc + 2] = vsrc.z; T[tr][tc + 3] = vsrc.w;
  __syncthreads();
  s4v o;
  o[0] = (short)f2bf_(T[tc + 0][tr]);
  o[1] = (short)f2bf_(T[tc + 1][tr]);
  o[2] = (short)f2bf_(T[tc + 2][tr]);
  o[3] = (short)f2bf_(T[tc + 3][tr]);
  *(s4v*)&dst[(size_t)(c0 + tr) * R + r0 + tc] = o;
}

// ---- qkv = x @ w_qkv via MFMA -> qb16/kb16 row-major bf16, vT16 bf16 -------
__global__ __launch_bounds__(256) void gemm_qkv_mfma(const float* __restrict__ x,
                                                     const short* __restrict__ wT,
                                                     short* __restrict__ qb16,
                                                     short* __restrict__ kb16,
                                                     short* __restrict__ vT16) {
  __shared__ short SMEM[17408];   // As[0..4095], Bs[4096..8191]; v: stage 128x136
  short* As = SMEM;
  short* Bs = SMEM + 4096;
  const int tid = threadIdx.x;
  const int lane = tid & 63, w = tid >> 6;
  const int wr = w >> 1, wc = w & 1;
  const int gm0 = blockIdx.x * 128, gn0 = blockIdx.y * 128;
  const int mA0 = (tid >> 6) * 16 + (tid & 15), kA0 = ((tid >> 4) & 3) * 8;
  const int s1 = tid + 256;
  const int mA1 = (s1 >> 6) * 16 + (s1 & 15), kA1 = ((s1 >> 4) & 3) * 8;
  f32x4 acc[4][4];
#pragma unroll
  for (int i = 0; i < 4; ++i)
#pragma unroll
    for (int j = 0; j < 4; ++j) acc[i][j] = (f32x4){0.f, 0.f, 0.f, 0.f};
  for (int kt = 0; kt < 16; ++kt) {
    const int k0 = kt * 32;
    float4 a0 = *(const float4*)&x[(size_t)(gm0 + mA0) * 512 + k0 + kA0];
    float4 a1 = *(const float4*)&x[(size_t)(gm0 + mA0) * 512 + k0 + kA0 + 4];
    float4 a2 = *(const float4*)&x[(size_t)(gm0 + mA1) * 512 + k0 + kA1];
    float4 a3 = *(const float4*)&x[(size_t)(gm0 + mA1) * 512 + k0 + kA1 + 4];
    bf8 b0 = *(const bf8*)&wT[(size_t)(gn0 + mA0) * 512 + k0 + kA0];
    bf8 b1 = *(const bf8*)&wT[(size_t)(gn0 + mA1) * 512 + k0 + kA1];
    __syncthreads();
    *(bf8*)&As[tid * 8] = pack8(a0, a1);
    *(bf8*)&As[s1 * 8] = pack8(a2, a3);
    *(bf8*)&Bs[tid * 8] = b0;
    *(bf8*)&Bs[s1 * 8] = b1;
    __syncthreads();
    bf8 af[4], bf[4];
#pragma unroll
    for (int i = 0; i < 4; ++i) {
      af[i] = *(const bf8*)&As[((wr * 4 + i) * 64 + lane) * 8];
      bf[i] = *(const bf8*)&Bs[((wc * 4 + i) * 64 + lane) * 8];
    }
#pragma unroll
    for (int i = 0; i < 4; ++i)
#pragma unroll
      for (int j = 0; j < 4; ++j)
        acc[i][j] = __builtin_amdgcn_mfma_f32_16x16x32_bf16(af[i], bf[j], acc[i][j], 0, 0, 0);
  }
  const int which = blockIdx.y >> 2;  // 0:q 1:k 2:v
  const int qd = lane >> 4, c = lane & 15;
  if (which < 2) {
    short* dst = which == 0 ? qb16 : kb16;
    const float scale = which == 0 ? 0.125f : 1.0f;
#pragma unroll
    for (int i = 0; i < 4; ++i)
#pragma unroll
      for (int j = 0; j < 4; ++j) {
        const int col = gn0 + wc * 64 + j * 16 + c;
        const int head = (col >> 6) & 7, dd = col & 63;
#pragma unroll
        for (int r = 0; r < 4; ++r) {
          const int row = gm0 + wr * 64 + i * 16 + qd * 4 + r;
          const int b = row >> 12, seq = row & 4095;
          dst[(size_t)(b * 8 + head) * QKV_STRIDE + seq * 64 + dd] =
              (short)f2bf_(acc[i][j][r] * scale);
        }
      }
  } else {
    // stage C tile as [colLocal][rowLocal] (stride 136) then coalesced vT writes
    __syncthreads();
#pragma unroll
    for (int i = 0; i < 4; ++i)
#pragma unroll
      for (int j = 0; j < 4; ++j) {
        const int colL = wc * 64 + j * 16 + c;
#pragma unroll
        for (int r = 0; r < 4; ++r) {
          const int rowL = wr * 64 + i * 16 + qd * 4 + r;
          SMEM[colL * 136 + rowL] = (short)f2bf_(acc[i][j][r]);
        }
      }
    __syncthreads();
    const int b = gm0 >> 12, seq0 = gm0 & 4095;
    const int dcol = tid >> 1, half = tid & 1;
    const int col = gn0 + dcol;
    const int head = (col >> 6) & 7, d = col & 63;
    const short* src = &SMEM[dcol * 136 + half * 64];
    short* dstp = &vT16[(size_t)(b * 8 + head) * QKV_STRIDE + (size_t)d * 4096 +
                        seq0 + half * 64];
#pragma unroll
    for (int u = 0; u < 16; ++u) *(s4v*)&dstp[u * 4] = *(const s4v*)&src[u * 4];
  }
}

// ---------------- landmark means (bf16 in, fp32 + bf16-kl out) --------------
__global__ __launch_bounds__(256) void lmk_mean(const short* __restrict__ qb16,
                                                const short* __restrict__ kb16,
                                                float* __restrict__ ql,
                                                float* __restrict__ kl,
                                                short* __restrict__ klb16) {
  const int g = blockIdx.x * 256 + threadIdx.x;
  const int dd = g & 63, mi = (g >> 6) & 255, bh = g >> 14;
  const size_t base = (size_t)bh * QKV_STRIDE + mi * 1024 + dd;
  float sq = 0.f, sk = 0.f;
#pragma unroll
  for (int jj = 0; jj < 16; ++jj) {
    sq += bf2f_((unsigned short)qb16[base + jj * 64]);
    sk += bf2f_((unsigned short)kb16[base + jj * 64]);
  }
  const float qv = sq * 0.0625f, kv = sk * 0.0625f;
  ql[g] = qv;
  kl[g] = kv;
  klb16[g] = (short)f2bf_(kv);
}

// ---------------- sim2 = ql @ kl^T, softmax -> x2 ---------------------------
__global__ __launch_bounds__(256) void sim2_softmax(const float* __restrict__ ql,
                                                    const float* __restrict__ kl,
                                                    float* __restrict__ x2) {
  const int blk = blockIdx.x;
  const int bh = blk >> 4, rg = blk & 15;
  __shared__ float Qs[16][64];
  __shared__ float Ks[64][68];
  __shared__ float S[16][257];
  __shared__ float red[16][17];
  __shared__ float rowinv[16];
  const int tid = threadIdx.x;
  const int r = tid >> 4, jc = tid & 15;
#pragma unroll
  for (int u = 0; u < 4; ++u) {
    int t2 = tid + u * 256;
    Qs[t2 >> 6][t2 & 63] =
        ql[(size_t)bh * LM_STRIDE + (rg * 16 + (t2 >> 6)) * 64 + (t2 & 63)];
  }
  for (int c = 0; c < 4; ++c) {
    __syncthreads();
#pragma unroll
    for (int u = 0; u < 4; ++u) {
      int t4 = tid + u * 256;
      int row = t4 >> 4, c4 = (t4 & 15) << 2;
      *(float4*)&Ks[row][c4] =
          *(const float4*)&kl[(size_t)bh * LM_STRIDE + (c * 64 + row) * 64 + c4];
    }
    __syncthreads();
#pragma unroll
    for (int s = 0; s < 4; ++s) {
      const int jj = jc + (s << 4);
      float acc = 0.f;
#pragma unroll
      for (int k4 = 0; k4 < 16; ++k4) {
        const float4 a = *(const float4*)&Qs[r][k4 << 2];
        const float4 bb = *(const float4*)&Ks[jj][k4 << 2];
        acc += a.x * bb.x + a.y * bb.y + a.z * bb.z + a.w * bb.w;
      }
      S[r][(c << 6) + jj] = acc;
    }
  }
  __syncthreads();
  float pm = -3.0e38f;
#pragma unroll
  for (int u = 0; u < 16; ++u) pm = fmaxf(pm, S[r][jc + (u << 4)]);
  red[r][jc] = pm;
  __syncthreads();
  float m = red[r][0];
#pragma unroll
  for (int u = 1; u < 16; ++u) m = fmaxf(m, red[r][u]);
  __syncthreads();
  float ps = 0.f;
#pragma unroll
  for (int u = 0; u < 16; ++u) {
    const int j = jc + (u << 4);
    const float e = __expf(S[r][j] - m);
    S[r][j] = e;
    ps += e;
  }
  red[r][jc] = ps;
  __syncthreads();
  if (jc == 0) {
    float sum = 0.f;
#pragma unroll
    for (int u = 0; u < 16; ++u) sum += red[r][u];
    rowinv[r] = 1.0f / sum;
  }
  __syncthreads();
  for (int idx = tid; idx < 4096; idx += 256) {
    const int rr = idx >> 8, j = idx & 255;
    x2[(size_t)bh * MM_STRIDE + (rg * 16 + rr) * 256 + j] = S[rr][j] * rowinv[rr];
  }
}

// ---------------- global max of col/row abs-sums ----------------------------
__global__ __launch_bounds__(256) void colrow_max(const float* __restrict__ x2,
                                                  float* __restrict__ scal) {
  const int bh = blockIdx.x;
  const int tid = threadIdx.x;
  const float* xb = x2 + (size_t)bh * MM_STRIDE;
  float cs = 0.f, rs = 0.f;
  for (int j = 0; j < 256; ++j) cs += fabsf(xb[tid * 256 + j]);
  for (int i = 0; i < 256; ++i) rs += fabsf(xb[i * 256 + tid]);
  __shared__ float rc[256], rr[256];
  rc[tid] = cs; rr[tid] = rs;
  __syncthreads();
  for (int st = 128; st > 0; st >>= 1) {
    if (tid < st) {
      rc[tid] = fmaxf(rc[tid], rc[tid + st]);
      rr[tid] = fmaxf(rr[tid], rr[tid + st]);
    }
    __syncthreads();
  }
  if (tid == 0) {
    atomicMax((int*)&scal[0], __float_as_int(rc[0]));
    atomicMax((int*)&scal[1], __float_as_int(rr[0]));
  }
}

// --------- z0 = x2^T/(cmax*rmax), z0t = x2/(cmax*rmax) ----------------------
__global__ __launch_bounds__(256) void tscale2(const float* __restrict__ x2,
                                               const float* __restrict__ scal,
                                               float* __restrict__ z0,
                                               float* __restrict__ z0t) {
  const int g = blockIdx.x * 256 + threadIdx.x;
  const int j = g & 255, i = (g >> 8) & 255, bh = g >> 16;
  const float inv = 1.0f / (scal[0] * scal[1]);
  const float val = x2[g] * inv;      // x2[bh][i][j]
  z0t[g] = val;
  z0[(size_t)bh * MM_STRIDE + j * 256 + i] = val;
}

// --------- split-bf16 batched 256^3: C = alpha*E + beta*(A@B) ---------------
__global__ __launch_bounds__(256) void pinv_mfma(const float* __restrict__ A,
                                                 const float* __restrict__ BT,
                                                 const float* __restrict__ E,
                                                 float* __restrict__ C,
                                                 float* __restrict__ CT,
                                                 float alpha, float beta,
                                                 int wantC, int wantT) {
  __shared__ short Ahi[2048], Alo[2048], Bhi[2048], Blo[2048];
  __shared__ float Tbuf[64 * 68];
  const int tid = threadIdx.x;
  const int lane = tid & 63, w = tid >> 6;
  const int bid = blockIdx.x;
  const int xcd = bid & 7, y = bid >> 3;
  const int t16 = y & 15, bgrp = y >> 4;
  const int batch = bgrp * 8 + xcd;
  const int tm = t16 >> 2, tn = t16 & 3;
  const float* Ab = A + (size_t)batch * MM_STRIDE;
  const float* BTb = BT + (size_t)batch * MM_STRIDE;
  const float* Eb = E + (size_t)batch * MM_STRIDE;
  const int ml = (tid >> 6) * 16 + (tid & 15), koff = ((tid >> 4) & 3) * 8;
  f32x4 acc[4];
#pragma unroll
  for (int j = 0; j < 4; ++j) acc[j] = (f32x4){0.f, 0.f, 0.f, 0.f};
  for (int kt = 0; kt < 8; ++kt) {
    const int k0 = kt * 32;
    float4 a0 = *(const float4*)&Ab[(size_t)(tm * 64 + ml) * 256 + k0 + koff];
    float4 a1 = *(const float4*)&Ab[(size_t)(tm * 64 + ml) * 256 + k0 + koff + 4];
    float4 b0 = *(const float4*)&BTb[(size_t)(tn * 64 + ml) * 256 + k0 + koff];
    float4 b1 = *(const float4*)&BTb[(size_t)(tn * 64 + ml) * 256 + k0 + koff + 4];
    __syncthreads();
    {
      bf8 hi, lo;
      const float fa[8] = {a0.x, a0.y, a0.z, a0.w, a1.x, a1.y, a1.z, a1.w};
#pragma unroll
      for (int e = 0; e < 8; ++e) {
        unsigned short h = f2bf_(fa[e]);
        hi[e] = (short)h;
        lo[e] = (short)f2bf_(fa[e] - bf2f_(h));
      }
      *(bf8*)&Ahi[tid * 8] = hi;
      *(bf8*)&Alo[tid * 8] = lo;
      const float fb[8] = {b0.x, b0.y, b0.z, b0.w, b1.x, b1.y, b1.z, b1.w};
#pragma unroll
      for (int e = 0; e < 8; ++e) {
        unsigned short h = f2bf_(fb[e]);
        hi[e] = (short)h;
        lo[e] = (short)f2bf_(fb[e] - bf2f_(h));
      }
      *(bf8*)&Bhi[tid * 8] = hi;
      *(bf8*)&Blo[tid * 8] = lo;
    }
    __syncthreads();
    bf8 ah = *(const bf8*)&Ahi[(w * 64 + lane) * 8];
    bf8 al = *(const bf8*)&Alo[(w * 64 + lane) * 8];
#pragma unroll
    for (int j = 0; j < 4; ++j) {
      bf8 bh = *(const bf8*)&Bhi[(j * 64 + lane) * 8];
      bf8 bl = *(const bf8*)&Blo[(j * 64 + lane) * 8];
      acc[j] = __builtin_amdgcn_mfma_f32_16x16x32_bf16(ah, bh, acc[j], 0, 0, 0);
      acc[j] = __builtin_amdgcn_mfma_f32_16x16x32_bf16(ah, bl, acc[j], 0, 0, 0);
      acc[j] = __builtin_amdgcn_mfma_f32_16x16x32_bf16(al, bh, acc[j], 0, 0, 0);
    }
  }
  float* Cb = C + (size_t)batch * MM_STRIDE;
  float* CTb = CT + (size_t)batch * MM_STRIDE;
  const int qd = lane >> 4, c = lane & 15;
  float vals[4][4];
#pragma unroll
  for (int j = 0; j < 4; ++j) {
    const int col = tn * 64 + j * 16 + c;
#pragma unroll
    for (int r = 0; r < 4; ++r) {
      const int row = tm * 64 + w * 16 + qd * 4 + r;
      vals[j][r] = alpha * Eb[(size_t)row * 256 + col] + beta * acc[j][r];
      if (wantC) Cb[(size_t)row * 256 + col] = vals[j][r];
    }
  }
  if (wantT) {
    __syncthreads();
#pragma unroll
    for (int j = 0; j < 4; ++j)
#pragma unroll
      for (int r = 0; r < 4; ++r)
        Tbuf[(j * 16 + c) * 68 + w * 16 + qd * 4 + r] = vals[j][r];
    __syncthreads();
    const int ctr = tid >> 2, seg = (tid & 3) * 16;
#pragma unroll
    for (int u = 0; u < 4; ++u) {
      float4 o = *(const float4*)&Tbuf[ctr * 68 + seg + u * 4];
      *(float4*)&CTb[(size_t)(tn * 64 + ctr) * 256 + tm * 64 + seg + u * 4] = o;
    }
  }
}

// ---- attn3 flash: O_part = exp(ql@k^T - m) @ v over a 1024-key chunk -------
__global__ __launch_bounds__(256) void attn3_flash(const float* __restrict__ ql,
                                                   const short* __restrict__ kb16,
                                                   const short* __restrict__ vT16,
                                                   float* __restrict__ opart,
                                                   float* __restrict__ mpart,
                                                   float* __restrict__ lpart) {
  const int kc = blockIdx.x;   // key chunk 0..3 (1024 keys each)
  const int rt = blockIdx.y;   // row tile 0..3 (64 rows each)
  const int bh = blockIdx.z;   // 0..31
  __shared__ short Pa[16384];  // 64 rows x 256 keys, A-frag order
  __shared__ float redM[4][64], redS[4][64];
  __shared__ float mRow[64], lRow[64], alphaRow[64];
  const int tid = threadIdx.x, lane = tid & 63, w = tid >> 6;
  const int qd = lane >> 4, c = lane & 15;
  const int r0 = rt * 64;
  const float* qlp = ql + (size_t)bh * LM_STRIDE;
  const short* kp = kb16 + (size_t)bh * QKV_STRIDE;
  const short* vp = vT16 + (size_t)bh * QKV_STRIDE;
  bf8 af[2][4];
#pragma unroll
  for (int st = 0; st < 2; ++st)
#pragma unroll
    for (int i = 0; i < 4; ++i) {
      float4 x0 = *(const float4*)&qlp[(size_t)(r0 + i * 16 + c) * 64 + st * 32 + qd * 8];
      float4 x1 = *(const float4*)&qlp[(size_t)(r0 + i * 16 + c) * 64 + st * 32 + qd * 8 + 4];
      af[st][i] = pack8(x0, x1);
    }
  if (tid < 64) { mRow[tid] = -3.0e38f; lRow[tid] = 0.f; }
  f32x4 accO[4];
#pragma unroll
  for (int nb = 0; nb < 4; ++nb) accO[nb] = (f32x4){0.f, 0.f, 0.f, 0.f};
  __syncthreads();
  for (int it = 0; it < 4; ++it) {
    const int kb0 = kc * 1024 + it * 256;
    f32x4 acc[4][4];
#pragma unroll
    for (int i = 0; i < 4; ++i)
#pragma unroll
      for (int j = 0; j < 4; ++j) acc[i][j] = (f32x4){0.f, 0.f, 0.f, 0.f};
#pragma unroll
    for (int st = 0; st < 2; ++st) {
      bf8 bfk[4];
#pragma unroll
      for (int j = 0; j < 4; ++j)
        bfk[j] = *(const bf8*)&kp[(size_t)(kb0 + w * 64 + j * 16 + c) * 64 + st * 32 + qd * 8];
#pragma unroll
      for (int i = 0; i < 4; ++i)
#pragma unroll
        for (int j = 0; j < 4; ++j)
          acc[i][j] = __builtin_amdgcn_mfma_f32_16x16x32_bf16(af[st][i], bfk[j], acc[i][j], 0, 0, 0);
    }
#pragma unroll
    for (int i = 0; i < 4; ++i)
#pragma unroll
      for (int r = 0; r < 4; ++r) {
        float m0 = fmaxf(fmaxf(acc[i][0][r], acc[i][1][r]),
                         fmaxf(acc[i][2][r], acc[i][3][r]));
        m0 = fmaxf(m0, __shfl_xor(m0, 1));
        m0 = fmaxf(m0, __shfl_xor(m0, 2));
        m0 = fmaxf(m0, __shfl_xor(m0, 4));
        m0 = fmaxf(m0, __shfl_xor(m0, 8));
        if (c == 0) redM[w][i * 16 + qd * 4 + r] = m0;
      }
    __syncthreads();
    if (tid < 64) {
      float mN = fmaxf(fmaxf(redM[0][tid], redM[1][tid]),
                       fmaxf(redM[2][tid], redM[3][tid]));
      mN = fmaxf(mN, mRow[tid]);
      const float a = __expf(mRow[tid] - mN);
      alphaRow[tid] = a;
      mRow[tid] = mN;
      lRow[tid] *= a;
    }
    __syncthreads();
#pragma unroll
    for (int r = 0; r < 4; ++r) {
      const float a = alphaRow[w * 16 + qd * 4 + r];
#pragma unroll
      for (int nb = 0; nb < 4; ++nb) accO[nb][r] *= a;
    }
#pragma unroll
    for (int i = 0; i < 4; ++i)
#pragma unroll
      for (int r = 0; r < 4; ++r) {
        const int row = i * 16 + qd * 4 + r;
        const float mrow = mRow[row];
        float s = 0.f;
#pragma unroll
        for (int j = 0; j < 4; ++j) {
          const float e = __expf(acc[i][j][r] - mrow);
          acc[i][j][r] = e;
          s += e;
        }
        s += __shfl_xor(s, 1);
        s += __shfl_xor(s, 2);
        s += __shfl_xor(s, 4);
        s += __shfl_xor(s, 8);
        if (c == 0) redS[w][row] = s;
      }
    __syncthreads();
    if (tid < 64)
      lRow[tid] += redS[0][tid] + redS[1][tid] + redS[2][tid] + redS[3][tid];
#pragma unroll
    for (int i = 0; i < 4; ++i)
#pragma unroll
      for (int r = 0; r < 4; ++r) {
        const int row = i * 16 + qd * 4 + r;
#pragma unroll
        for (int j = 0; j < 4; ++j) {
          const int col = w * 64 + j * 16 + c;
          const int kbk = col >> 5;
          const int lane2 = (row & 15) + 16 * ((col >> 3) & 3);
          Pa[((kbk * 4 + i) * 64 + lane2) * 8 + (col & 7)] = (short)f2bf_(acc[i][j][r]);
        }
      }
    __syncthreads();
#pragma unroll
    for (int kbk = 0; kbk < 8; ++kbk) {
      bf8 ap = *(const bf8*)&Pa[((kbk * 4 + w) * 64 + lane) * 8];
#pragma unroll
      for (int nb = 0; nb < 4; ++nb) {
        bf8 bv = *(const bf8*)&vp[(size_t)(nb * 16 + c) * 4096 + kb0 + kbk * 32 + qd * 8];
        accO[nb] = __builtin_amdgcn_mfma_f32_16x16x32_bf16(ap, bv, accO[nb], 0, 0, 0);
      }
    }
    __syncthreads();
  }
  const size_t ob = ((size_t)kc * 32 + bh) * 256 + r0;
#pragma unroll
  for (int nb = 0; nb < 4; ++nb)
#pragma unroll
    for (int r = 0; r < 4; ++r)
      opart[(ob + w * 16 + qd * 4 + r) * 64 + nb * 16 + c] = accO[nb][r];
  if (tid < 64) {
    mpart[ob + tid] = mRow[tid];
    lpart[ob + tid] = lRow[tid];
  }
}

// ---------------- merge the 4 key-chunk partials -> av ----------------------
__global__ __launch_bounds__(256) void attn3_merge(const float* __restrict__ opart,
                                                   const float* __restrict__ mpart,
                                                   const float* __restrict__ lpart,
                                                   float* __restrict__ av) {
  const int g = blockIdx.x * 256 + threadIdx.x;   // 524288 = 32*256*64
  const int d = g & 63;
  const int idx = g >> 6;                          // bh*256+row
  const float m0 = mpart[idx], m1 = mpart[8192 + idx],
              m2 = mpart[16384 + idx], m3 = mpart[24576 + idx];
  const float mx = fmaxf(fmaxf(m0, m1), fmaxf(m2, m3));
  const float w0 = __expf(m0 - mx), w1 = __expf(m1 - mx),
              w2 = __expf(m2 - mx), w3 = __expf(m3 - mx);
  const float l = lpart[idx] * w0 + lpart[8192 + idx] * w1 +
                  lpart[16384 + idx] * w2 + lpart[24576 + idx] * w3;
  const float o = opart[(size_t)idx * 64 + d] * w0 +
                  opart[524288 + (size_t)idx * 64 + d] * w1 +
                  opart[1048576 + (size_t)idx * 64 + d] * w2 +
                  opart[1572864 + (size_t)idx * 64 + d] * w3;
  av[g] = o / l;
}

// ------- w2^T = (z_final @ av)^T : stores bf16 w2tb16[d][i] -----------------
__global__ __launch_bounds__(256) void zav_gemm_t(const float* __restrict__ z,
                                                  const float* __restrict__ av,
                                                  short* __restrict__ w2tb16) {
  const int bh = blockIdx.x;
  const int rq = blockIdx.y;
  __shared__ float Av[256][64];
  const int tid = threadIdx.x;
#pragma unroll
  for (int u = 0; u < 16; ++u) {
    int t4 = tid + u * 256;
    int row = t4 >> 4, c4 = (t4 & 15) << 2;
    *(float4*)&Av[row][c4] = *(const float4*)&av[(size_t)bh * LM_STRIDE + row * 64 + c4];
  }
  __syncthreads();
  const int d = tid & 63, rg4 = tid >> 6;
  for (int s = 0; s < 16; ++s) {
    const int i = rq * 64 + s * 4 + rg4;
    const float* zr = z + (size_t)bh * MM_STRIDE + i * 256;
    float acc = 0.f;
#pragma unroll 8
    for (int j = 0; j < 256; ++j) acc += zr[j] * Av[j][d];
    w2tb16[(size_t)bh * LM_STRIDE + d * 256 + i] = (short)f2bf_(acc);
  }
}

// -- attn1+conv: oh = softmax(q@kl^T)@w2 + conv(v) [conv via banded MFMA] ----
__global__ __launch_bounds__(256) void attn1_conv_mfma(const short* __restrict__ qb16,
                                                       const short* __restrict__ klb16,
                                                       const short* __restrict__ w2tb16,
                                                       const short* __restrict__ vT16,
                                                       const float* __restrict__ cw,
                                                       short* __restrict__ ohb16) {
  __shared__ short Pa[16384];               // 64x256 bf16 in A-frag order
  __shared__ float redM[4][64], redS[4][64];
  __shared__ float rowM[64], rowI[64];
  __shared__ float cwS[33];
  const int tid = threadIdx.x;
  const int lane = tid & 63, w = tid >> 6;
  const int qd = lane >> 4, c = lane & 15;
  const int r0 = blockIdx.x * 64;
  const int bh = blockIdx.y;
  const short* qp = qb16 + (size_t)bh * QKV_STRIDE;
  const short* klp = klb16 + (size_t)bh * LM_STRIDE;
  const short* w2p = w2tb16 + (size_t)bh * LM_STRIDE;
  const short* vp = vT16 + (size_t)bh * QKV_STRIDE;

  if (tid < 33) cwS[tid] = cw[(bh & 7) * 33 + tid];

  f32x4 acc[4][4];
#pragma unroll
  for (int i = 0; i < 4; ++i)
#pragma unroll
    for (int j = 0; j < 4; ++j) acc[i][j] = (f32x4){0.f, 0.f, 0.f, 0.f};
#pragma unroll
  for (int st = 0; st < 2; ++st) {
    const int k0 = st * 32 + qd * 8;
    bf8 af[4], bf[4];
#pragma unroll
    for (int i = 0; i < 4; ++i) {
      af[i] = *(const bf8*)&qp[(size_t)(r0 + i * 16 + c) * 64 + k0];
      bf[i] = *(const bf8*)&klp[(size_t)(w * 64 + i * 16 + c) * 64 + k0];
    }
#pragma unroll
    for (int i = 0; i < 4; ++i)
#pragma unroll
      for (int j = 0; j < 4; ++j)
        acc[i][j] = __builtin_amdgcn_mfma_f32_16x16x32_bf16(af[i], bf[j], acc[i][j], 0, 0, 0);
  }
#pragma unroll
  for (int i = 0; i < 4; ++i)
#pragma unroll
    for (int r = 0; r < 4; ++r) {
      float m0 = fmaxf(fmaxf(acc[i][0][r], acc[i][1][r]),
                       fmaxf(acc[i][2][r], acc[i][3][r]));
      m0 = fmaxf(m0, __shfl_xor(m0, 1));
      m0 = fmaxf(m0, __shfl_xor(m0, 2));
      m0 = fmaxf(m0, __shfl_xor(m0, 4));
      m0 = fmaxf(m0, __shfl_xor(m0, 8));
      if (c == 0) redM[w][i * 16 + qd * 4 + r] = m0;
    }
  __syncthreads();
  if (tid < 64)
    rowM[tid] = fmaxf(fmaxf(redM[0][tid], redM[1][tid]),
                      fmaxf(redM[2][tid], redM[3][tid]));
  __syncthreads();
#pragma unroll
  for (int i = 0; i < 4; ++i)
#pragma unroll
    for (int r = 0; r < 4; ++r) {
      const float mrow = rowM[i * 16 + qd * 4 + r];
      float s = 0.f;
#pragma unroll
      for (int j = 0; j < 4; ++j) {
        const float e = __expf(acc[i][j][r] - mrow);
        acc[i][j][r] = e;
        s += e;
      }
      s += __shfl_xor(s, 1);
      s += __shfl_xor(s, 2);
      s += __shfl_xor(s, 4);
      s += __shfl_xor(s, 8);
      if (c == 0) redS[w][i * 16 + qd * 4 + r] = s;
    }
  __syncthreads();
  if (tid < 64)
    rowI[tid] = 1.0f / (redS[0][tid] + redS[1][tid] + redS[2][tid] + redS[3][tid]);
  __syncthreads();
#pragma unroll
  for (int i = 0; i < 4; ++i)
#pragma unroll
    for (int r = 0; r < 4; ++r) {
      const int row = i * 16 + qd * 4 + r;
      const float inv = rowI[row];
#pragma unroll
      for (int j = 0; j < 4; ++j) {
        const int col = w * 64 + j * 16 + c;
        const short val = (short)f2bf_(acc[i][j][r] * inv);
        const int kb = col >> 5;
        const int lane2 = (row & 15) + 16 * ((col >> 3) & 3);
        Pa[((kb * 4 + i) * 64 + lane2) * 8 + (col & 7)] = val;
      }
    }
  __syncthreads();
  f32x4 accO[4];
#pragma unroll
  for (int nb = 0; nb < 4; ++nb) accO[nb] = (f32x4){0.f, 0.f, 0.f, 0.f};
  for (int kb = 0; kb < 8; ++kb) {
    bf8 ap = *(const bf8*)&Pa[((kb * 4 + w) * 64 + lane) * 8];
#pragma unroll
    for (int nb = 0; nb < 4; ++nb) {
      bf8 bfr = *(const bf8*)&w2p[(size_t)(nb * 16 + c) * 256 + kb * 32 + qd * 8];
      accO[nb] = __builtin_amdgcn_mfma_f32_16x16x32_bf16(ap, bfr, accO[nb], 0, 0, 0);
    }
  }
  // conv residual via banded MFMA: out += Band[64x96] @ Vwin[96x64]
  // Band[rl][k] = cw[k-rl] when 0<=k-rl<33 and 0<=r0-16+k<4096
  {
    bf8 ba[3];
    const int rl = w * 16 + (lane & 15);   // A-frag row (m = lane&15)
#pragma unroll
    for (int kb = 0; kb < 3; ++kb) {
#pragma unroll
      for (int e = 0; e < 8; ++e) {
        const int kk = kb * 32 + qd * 8 + e;
        const int t = kk - rl;
        const int s = r0 - 16 + kk;
        const float bv = (t >= 0 && t < 33 && s >= 0 && s < 4096) ? cwS[t] : 0.f;
        ba[kb][e] = (short)f2bf_(bv);
      }
    }
#pragma unroll
    for (int kb = 0; kb < 3; ++kb) {
      int s0 = r0 - 16 + kb * 32 + qd * 8;
      s0 = s0 < 0 ? 0 : (s0 > 4088 ? 4088 : s0);
#pragma unroll
      for (int nb = 0; nb < 4; ++nb) {
        bf8 bv = *(const bf8*)&vp[(size_t)(nb * 16 + c) * 4096 + s0];
        accO[nb] = __builtin_amdgcn_mfma_f32_16x16x32_bf16(ba[kb], bv, accO[nb], 0, 0, 0);
      }
    }
  }
  short* ohp = (short*)ohb16 + (size_t)bh * QKV_STRIDE;
#pragma unroll
  for (int nb = 0; nb < 4; ++nb)
#pragma unroll
    for (int r = 0; r < 4; ++r) {
      const int row = r0 + w * 16 + qd * 4 + r;
      ohp[(size_t)row * 64 + nb * 16 + c] = (short)f2bf_(accO[nb][r]);
    }
}

// ------- out = concat_heads(oh_bf16) @ w_out + b_out (MFMA) -----------------
__global__ __launch_bounds__(256) void gemm_out_mfma(const short* __restrict__ ohb16,
                                                     const short* __restrict__ wT,
                                                     const float* __restrict__ bias,
                                                     float* __restrict__ out) {
  __shared__ short As[4096];
  __shared__ short Bs[4096];
  const int tid = threadIdx.x;
  const int lane = tid & 63, w = tid >> 6;
  const int wr = w >> 1, wc = w & 1;
  const int gm0 = blockIdx.x * 128, gn0 = blockIdx.y * 128;
  const int mA0 = (tid >> 6) * 16 + (tid & 15), kA0 = ((tid >> 4) & 3) * 8;
  const int s1 = tid + 256;
  const int mA1 = (s1 >> 6) * 16 + (s1 & 15), kA1 = ((s1 >> 4) & 3) * 8;
  const int b0r = (gm0 + mA0) >> 12, seq0 = (gm0 + mA0) & 4095;
  const int b1r = (gm0 + mA1) >> 12, seq1 = (gm0 + mA1) & 4095;
  f32x4 acc[4][4];
#pragma unroll
  for (int i = 0; i < 4; ++i)
#pragma unroll
    for (int j = 0; j < 4; ++j) acc[i][j] = (f32x4){0.f, 0.f, 0.f, 0.f};
  for (int kt = 0; kt < 16; ++kt) {
    const int k0 = kt * 32;
    const int ka = k0 + kA0, kb = k0 + kA1;
    bf8 aa0 = *(const bf8*)&ohb16[(size_t)(b0r * 8 + (ka >> 6)) * QKV_STRIDE + seq0 * 64 + (ka & 63)];
    bf8 aa1 = *(const bf8*)&ohb16[(size_t)(b1r * 8 + (kb >> 6)) * QKV_STRIDE + seq1 * 64 + (kb & 63)];
    bf8 bb0 = *(const bf8*)&wT[(size_t)(gn0 + mA0) * 512 + ka];
    bf8 bb1 = *(const bf8*)&wT[(size_t)(gn0 + mA1) * 512 + kb];
    __syncthreads();
    *(bf8*)&As[tid * 8] = aa0;
    *(bf8*)&As[s1 * 8] = aa1;
    *(bf8*)&Bs[tid * 8] = bb0;
    *(bf8*)&Bs[s1 * 8] = bb1;
    __syncthreads();
    bf8 af[4], bfr[4];
#pragma unroll
    for (int i = 0; i < 4; ++i) {
      af[i] = *(const bf8*)&As[((wr * 4 + i) * 64 + lane) * 8];
      bfr[i] = *(const bf8*)&Bs[((wc * 4 + i) * 64 + lane) * 8];
    }
#pragma unroll
    for (int i = 0; i < 4; ++i)
#pragma unroll
      for (int j = 0; j < 4; ++j)
        acc[i][j] = __builtin_amdgcn_mfma_f32_16x16x32_bf16(af[i], bfr[j], acc[i][j], 0, 0, 0);
  }
  const int qd = lane >> 4, c = lane & 15;
#pragma unroll
  for (int i = 0; i < 4; ++i)
#pragma unroll
    for (int j = 0; j < 4; ++j) {
      const int col = gn0 + wc * 64 + j * 16 + c;
      const float bval = bias[col];
#pragma unroll
      for (int r = 0; r < 4; ++r) {
        const int row = gm0 + wr * 64 + i * 16 + qd * 4 + r;
        out[(size_t)row * 512 + col] = acc[i][j][r] + bval;
      }
    }
}

// ---------------------------------------------------------------------------
extern "C" void kernel_launch(void* const* d_in, const int* in_sizes, int n_in,
                              void* d_out, int out_size, void* d_ws, size_t ws_size,
                              hipStream_t stream) {
  const float* x    = (const float*)d_in[0];
  const float* wqkv = (const float*)d_in[1];
  const float* wout = (const float*)d_in[2];
  const float* bout = (const float*)d_in[3];
  const float* cw   = (const float*)d_in[4];
  float* out = (float*)d_out;

  float* w = (float*)d_ws;
  short* qb16   = (short*)(w);              // [32,4096,64] bf16
  short* kb16   = (short*)(w + 4194304);    // [32,4096,64] bf16
  short* vT16   = (short*)(w + 8388608);    // [32,64,4096] bf16
  short* ohb16  = (short*)(w + 12582912);   // [32,4096,64] bf16
  float* ql     = w + 16777216;             // [32,256,64]
  float* kl     = w + 17301504;
  short* klb16  = (short*)(w + 17825792);   // [32,256,64] bf16
  float* x2     = w + 18087936;             // [32,256,256]
  float* z0     = w + 20185088;
  float* z0t    = w + 22282240;
  float* z1     = w + 24379392;
  float* z1t    = w + 26476544;
  float* xz     = w + 28573696;
  float* xzt    = w + 30670848;
  float* u1t    = w + 32768000;
  float* u2t    = w + 34865152;
  float* av     = w + 36962304;             // [32,256,64]
  short* w2tb16 = (short*)(w + 37486592);   // [32,64,256] bf16
  float* scal   = w + 37748736;             // [2]
  short* wqkvT  = (short*)(w + 37748800);   // [1536,512] bf16
  short* woutT  = (short*)(w + 38142016);   // [512,512] bf16
  // aliases valid only AFTER the pinv loop (z1/z1t dead; final z in z0):
  float* opart = z1;                        // [4,32,256,64]
  float* mpart = z1t;                       // [4,32,256]
  float* lpart = z1t + 32768;               // [4,32,256]

  zero_scal<<<1, 64, 0, stream>>>(scal);
  transpose_bf16<<<dim3(48, 16), 256, 0, stream>>>(wqkv, wqkvT, 512, 1536);
  transpose_bf16<<<dim3(16, 16), 256, 0, stream>>>(wout, woutT, 512, 512);
  gemm_qkv_mfma<<<dim3(128, 12), 256, 0, stream>>>(x, wqkvT, qb16, kb16, vT16);
  lmk_mean<<<2048, 256, 0, stream>>>(qb16, kb16, ql, kl, klb16);
  sim2_softmax<<<512, 256, 0, stream>>>(ql, kl, x2);
  colrow_max<<<32, 256, 0, stream>>>(x2, scal);
  tscale2<<<8192, 256, 0, stream>>>(x2, scal, z0, z0t);

  float *zc = z0, *zct = z0t, *zn = z1, *znt = z1t;
  for (int it = 0; it < 6; ++it) {
    pinv_mfma<<<512, 256, 0, stream>>>(x2, zct, x2, xz, xzt, 0.f, 1.f, 1, 1);
    pinv_mfma<<<512, 256, 0, stream>>>(xz, xzt, xz, u1t, u1t, 7.f, -1.f, 0, 1);
    pinv_mfma<<<512, 256, 0, stream>>>(xz, u1t, xz, u2t, u2t, 15.f, -1.f, 0, 1);
    pinv_mfma<<<512, 256, 0, stream>>>(zc, u2t, zc, zn, znt, 3.25f, -0.25f, 1, 1);
    float* t;
    t = zc; zc = zn; zn = t;
    t = zct; zct = znt; znt = t;
  }
  // zc == z0 here; z1/z1t dead -> opart/mpart/lpart aliases live.

  attn3_flash<<<dim3(4, 4, 32), 256, 0, stream>>>(ql, kb16, vT16, opart, mpart, lpart);
  attn3_merge<<<2048, 256, 0, stream>>>(opart, mpart, lpart, av);
  zav_gemm_t<<<dim3(32, 4), 256, 0, stream>>>(zc, av, w2tb16);
  attn1_conv_mfma<<<dim3(64, 32), 256, 0, stream>>>(qb16, klb16, w2tb16, vT16, cw, ohb16);
  gemm_out_mfma<<<dim3(128, 4), 256, 0, stream>>>(ohb16, woutT, bout, out);
}